// Round 7
// baseline (181.331 us; speedup 1.0000x reference)
//
#include <hip/hip_runtime.h>

#define B_   64
#define CIN_ 512
#define H_   512
#define V_   512
#define S_   32
#define T_   16
#define A_   256
#define SQN_ 3
#define BS_  2048   // B_*S_

typedef float  f32x4  __attribute__((ext_vector_type(4)));
typedef float  f32x2  __attribute__((ext_vector_type(2)));
typedef short  short8 __attribute__((ext_vector_type(8)));
typedef short  short4v __attribute__((ext_vector_type(4)));
typedef unsigned int uint4v __attribute__((ext_vector_type(4)));

__device__ __forceinline__ unsigned short f2bf(float f) {
    union { float f; unsigned int u; } v; v.f = f;
    unsigned int u = v.u;
    unsigned int r = (u + 0x7fffu + ((u >> 16) & 1u)) >> 16;
    return (unsigned short)r;
}
__device__ __forceinline__ float bf2f(unsigned short h) {
    union { unsigned int u; float f; } v; v.u = ((unsigned int)h) << 16;
    return v.f;
}

// fast tanh: (e-1)*rcp(e+1), e=exp(2x) via v_exp_f32; clamp keeps e finite.
__device__ __forceinline__ float fast_tanhf(float x) {
    float cx = fminf(fmaxf(x, -15.0f), 15.0f);
    float e  = __expf(2.0f * cx);
    return (e - 1.0f) * __builtin_amdgcn_rcpf(e + 1.0f);
}

// async global->LDS, 16 B per lane; lds dest = wave-uniform base + lane*16
__device__ __forceinline__ void gload16(const void* g, void* l) {
    __builtin_amdgcn_global_load_lds(
        (const __attribute__((address_space(1))) unsigned int*)g,
        (__attribute__((address_space(3))) unsigned int*)l,
        16, 0, 0);
}

template <int N> __device__ __forceinline__ void waitv() {
    asm volatile("s_waitcnt vmcnt(%0)" :: "n"(N) : "memory");
}

// ---------------------------------------------------------------------------
// prep_kernel (merged, one launch):
//   [0,128)      text split-K f32 partials: nt=id&7 (64n), kc=id>>3 (32k)
//   [128,131)    bcomb: 3 blocks (one per m), coalesced row-walk
//   [131,227)    glob_w f32 -> bf16 cast (8192 floats/block)
//   [227,547)    weight transposes (64x64)
//   [547,2595)   visual transpose-cast, DMA-staged [64k][128v] tiles
// ---------------------------------------------------------------------------
__global__ __launch_bounds__(256) void prep_kernel(
    const float* __restrict__ visual, const float* __restrict__ vis_conv_w,
    const float* __restrict__ att2_w, const float* __restrict__ guide_w,
    const float* __restrict__ att1_w, const float* __restrict__ out_conv_w,
    const float* __restrict__ glob_w, const float* __restrict__ text_feature,
    const float* __restrict__ text_w, const float* __restrict__ text_b,
    const float* __restrict__ glob_b, const float* __restrict__ guide_b,
    unsigned short* __restrict__ visT, unsigned short* __restrict__ wT_visconv,
    unsigned short* __restrict__ wT_att2, unsigned short* __restrict__ wT_guide,
    unsigned short* __restrict__ wT_att1, unsigned short* __restrict__ wT_out,
    unsigned short* __restrict__ glob_bf, float* __restrict__ text_part,
    float* __restrict__ bcomb)
{
    __shared__ __align__(16) char smem[32768];
    const int id  = blockIdx.x;
    const int tid = threadIdx.x;

    if (id < 128) {  // text split-K partial: [64m x 64n] over K=32, f32 exact
        const int nt = id & 7, kc = id >> 3;
        const int n0 = nt * 64, kbase = kc * 32;
        float* Ts = (float*)smem;                 // [64][33]
        float* Ws = (float*)smem + 64 * 33;       // [32][65]
        {
            const int m = tid >> 2, kk = (tid & 3) * 8;
            #pragma unroll
            for (int c = 0; c < 8; c += 4)
                *(f32x4*)&Ts[m * 33 + kk + c] =
                    *(const f32x4*)&text_feature[m * 512 + kbase + kk + c];
            const int kr = tid >> 3, nn = (tid & 7) * 8;
            #pragma unroll
            for (int c = 0; c < 8; c += 4)
                *(f32x4*)&Ws[kr * 65 + nn + c] =
                    *(const f32x4*)&text_w[(long long)(kbase + kr) * 512 + n0 + nn + c];
        }
        __syncthreads();
        const int tm = (tid >> 4) * 4, tn = (tid & 15) * 4;
        float acc[4][4] = {};
        for (int k = 0; k < 32; k++) {
            float a[4], b2[4];
            #pragma unroll
            for (int i = 0; i < 4; i++) a[i] = Ts[(tm + i) * 33 + k];
            #pragma unroll
            for (int j = 0; j < 4; j++) b2[j] = Ws[k * 65 + tn + j];
            #pragma unroll
            for (int i = 0; i < 4; i++)
                #pragma unroll
                for (int j = 0; j < 4; j++) acc[i][j] += a[i] * b2[j];
        }
        #pragma unroll
        for (int i = 0; i < 4; i++)
            #pragma unroll
            for (int j = 0; j < 4; j++)
                text_part[kc * (64 * 512) + (tm + i) * 512 + n0 + tn + j] =
                    acc[i][j] + (kc == 0 ? text_b[n0 + tn + j] : 0.0f);
        return;
    }
    if (id < 131) {  // bcomb[m][j] = glob_b[m] @ guide_w_top[:,j] + guide_b[j]
        const int m = id - 128;
        const int j2 = tid * 2;
        float a0 = guide_b[j2], a1 = guide_b[j2 + 1];
        const float* gb = glob_b + m * 512;
        #pragma unroll 8
        for (int k = 0; k < 512; k++) {
            const float g = gb[k];
            f32x2 w = *(const f32x2*)&guide_w[(long long)k * 512 + j2];  // coalesced
            a0 += g * w[0];
            a1 += g * w[1];
        }
        f32x2 o = {a0, a1};
        *(f32x2*)&bcomb[m * 512 + j2] = o;
        return;
    }
    if (id < 227) {  // glob cast: 8192 floats/block
        const int base = (id - 131) * 8192 + tid * 4;
        #pragma unroll
        for (int it = 0; it < 8; it++) {
            f32x4 v = *(const f32x4*)&glob_w[base + it * 1024];
            short4v o;
            #pragma unroll
            for (int c = 0; c < 4; c++) o[c] = (short)f2bf(v[c]);
            *(short4v*)&glob_bf[base + it * 1024] = o;
        }
        return;
    }

    if (id >= 547) {
        // visual transpose-cast: DMA-staged [64k][128v] tile
        const int q = id - 547;
        const int b = q >> 5, tile = q & 31;
        const int k0 = (tile >> 2) << 6;   // 0..448
        const int v0 = (tile & 3) << 7;    // 0,128,256,384
        const float* src = visual + (long long)b * 262144;
        unsigned short* dst = visT + (long long)b * 262144;
        float* tl = (float*)smem;          // [64][128] linear, 32 KB

        const int wave = tid >> 6, lane = tid & 63;
        #pragma unroll
        for (int i = 0; i < 8; i++) {
            const int r2 = wave * 16 + i * 2;
            gload16(&src[(long long)(k0 + r2 + (lane >> 5)) * 512 + v0 + (lane & 31) * 4],
                    &tl[r2 * 128]);
        }
        __syncthreads();

        const int kl = (tid & 7) * 8;      // 0..56
        const int vb = tid >> 3;           // 0..31
        #pragma unroll
        for (int jv = 0; jv < 4; jv++) {
            const int v = vb + jv * 32;
            short8 o;
            #pragma unroll
            for (int i = 0; i < 8; i++)
                o[i] = (short)f2bf(tl[(kl + i) * 128 + v]);
            *(short8*)&dst[(long long)(v0 + v) * 512 + k0 + kl] = o;
        }
        return;
    }

    // 64x64 transpose-cast (weights): src f32 [Kd][Nd] -> dst bf16 [Nd][Kd]
    const float* src; unsigned short* dst; int Kd, Nd, tile;
    if (id < 291)      { tile = id - 227; src = vis_conv_w; dst = wT_visconv; Kd = 512;  Nd = 512; }
    else if (id < 323) { tile = id - 291; src = att2_w;     dst = wT_att2;    Kd = 512;  Nd = 256; }
    else if (id < 451) { tile = id - 323; src = guide_w;    dst = wT_guide;   Kd = 1024; Nd = 512; }
    else if (id < 483) { tile = id - 451; src = att1_w;     dst = wT_att1;    Kd = 512;  Nd = 256; }
    else               { tile = id - 483; src = out_conv_w; dst = wT_out;     Kd = 512;  Nd = 512; }

    unsigned int* tl = (unsigned int*)smem;  // [64][65]
    const int xw = Nd >> 6;
    const int n0 = (tile % xw) << 6, k0 = (tile / xw) << 6;
    {
        const int r = tid >> 4;
        const int c4 = (tid & 15) * 4;
        #pragma unroll
        for (int j = 0; j < 4; j++) {
            const int row = j * 16 + r;
            f32x4 v = *(const f32x4*)&src[(long long)(k0 + row) * Nd + n0 + c4];
            #pragma unroll
            for (int c2 = 0; c2 < 4; c2++)
                tl[row * 65 + c4 + c2] = f2bf(v[c2]);
        }
    }
    __syncthreads();
    {
        const int v = tid >> 2, cq = (tid & 3) * 16;
        short8 o0, o1;
        #pragma unroll
        for (int j = 0; j < 8; j++) o0[j] = (short)tl[(cq + j) * 65 + v];
        #pragma unroll
        for (int j = 0; j < 8; j++) o1[j] = (short)tl[(cq + 8 + j) * 65 + v];
        *(short8*)&dst[(long long)(n0 + v) * Kd + k0 + cq] = o0;
        *(short8*)&dst[(long long)(n0 + v) * Kd + k0 + cq + 8] = o1;
    }
}

// ---------------------------------------------------------------------------
// GEMM body. vs r4: K-loop restructured to the validated single-barrier
// 2-phase (T3 minimum form, m230/m248):
//   stage(next) -> ds_read(cur) -> MFMA -> vmcnt(0) -> ONE s_barrier
// The load-drain now overlaps the MFMA phase instead of preceding it, and
// there is one collective sync per K-step instead of two.
// Safety: stage(kt) writes buf^1 whose last readers (step kt-1) completed
// their ds_reads (lgkmcnt before MFMA(kt-1)) before barrier(kt-1) < stage(kt).
// Reads of buf[cur] at kt are covered by kt-1's trailing vmcnt(0)+barrier.
// LDS XOR swizzle (both-sides, r4-proven) retained.
// ---------------------------------------------------------------------------
template <int BM, int BN, bool RELU, bool OUT_BF16, int OUT_MODE, bool ACC_INIT>
__device__ __forceinline__ void gemm_body(
    char* pool, int bid, int nwg,
    const unsigned short* __restrict__ A, long long aBatch, int lda,
    const unsigned short* __restrict__ Bt, long long bBatch, int ldb,
    const float* __restrict__ bias, long long biasBatch,
    const float* __restrict__ Cinit, int ldci,
    void* __restrict__ C, long long cBatch, int ldc,
    void* __restrict__ C2, unsigned short* __restrict__ avg_out,
    int M, int N, int K)
{
    constexpr int WM = BM / 2, WN = BN / 2;
    constexpr int FI = WM / 16, FJ = WN / 16;
    constexpr bool CT_EN  = (OUT_MODE != 1);
    constexpr bool CT_F32 = CT_EN && ((OUT_MODE == 0 && !OUT_BF16) || OUT_MODE == 3);
    constexpr int  CTS    = CT_F32 ? (BN + 4) : (BN + 8);
    constexpr int  KLOOP_B = 2 * (BM * 32 + BN * 32) * 2;
    constexpr int  CT_B    = CT_EN ? (BM * CTS * (CT_F32 ? 4 : 2)) : 0;
    constexpr int  MAIN_B  = (KLOOP_B > CT_B ? KLOOP_B : CT_B);
    unsigned short* As = (unsigned short*)pool;
    unsigned short* Bs = As + 2 * BM * 32;
    float* avgl = (float*)(pool + MAIN_B);

    // XCD-chunked bijective swizzle (m204)
    const int q8 = nwg >> 3, r8 = nwg & 7;
    const int xcd = bid & 7, lid = bid >> 3;
    const int logical = (xcd < r8 ? xcd * (q8 + 1)
                                  : r8 * (q8 + 1) + (xcd - r8) * q8) + lid;

    const int ntiles = N / BN;
    const int tilesPerBatch = (M / BM) * ntiles;
    const int batch = logical / tilesPerBatch;
    const int t     = logical % tilesPerBatch;
    const int tm0 = (t / ntiles) * BM;
    const int tn0 = (t % ntiles) * BN;
    const unsigned short* Ab = A + (long long)batch * aBatch;
    const unsigned short* Bb = Bt + (long long)batch * bBatch;

    const int tid  = threadIdx.x;
    const int lane = tid & 63;
    const int wave = tid >> 6;
    const int wm = (wave >> 1) * WM;
    const int wn = (wave & 1) * WN;
    const int lr = lane & 15;
    const int lk = (lane >> 4) * 8;
    const int rsub = lane >> 2;
    // pre-swizzled global 16B slot: (lane&3) ^ ((lane>>3)&3) == (lane&3) ^ ((row>>1)&3)
    const int g8s = ((lane & 3) ^ ((lane >> 3) & 3)) * 8;
    // frag-read elem offset with matching XOR (row key = (lr>>1)&3)
    const int lks = lk ^ (((lr >> 1) & 3) << 3);

    auto stage = [&](int buf, int k0) {
        #pragma unroll
        for (int i = 0; i < BM / 64; i++) {
            const int rbase = wave * (BM / 4) + i * 16;
            gload16(&Ab[(long long)(tm0 + rbase + rsub) * lda + k0 + g8s],
                    &As[buf * (BM * 32) + rbase * 32]);
        }
        #pragma unroll
        for (int i = 0; i < BN / 64; i++) {
            const int rbase = wave * (BN / 4) + i * 16;
            gload16(&Bb[(long long)(tn0 + rbase + rsub) * ldb + k0 + g8s],
                    &Bs[buf * (BN * 32) + rbase * 32]);
        }
    };

    f32x4 acc[FI][FJ] = {};
    const int nk = K >> 5;

    // prologue: stage tile 0, drain, publish
    stage(0, 0);
    waitv<0>();
    __builtin_amdgcn_s_barrier();

    int cur = 0;
    for (int kt = 0; kt < nk; kt++) {
        if (kt + 1 < nk) stage(cur ^ 1, (kt + 1) << 5);

        const unsigned short* Ac = As + cur * (BM * 32);
        const unsigned short* Bc = Bs + cur * (BN * 32);
        short8 a[FI], b[FJ];
        #pragma unroll
        for (int i = 0; i < FI; i++)
            a[i] = *(const short8*)&Ac[(wm + i * 16 + lr) * 32 + lks];
        #pragma unroll
        for (int j = 0; j < FJ; j++)
            b[j] = *(const short8*)&Bc[(wn + j * 16 + lr) * 32 + lks];
        #pragma unroll
        for (int i = 0; i < FI; i++)
            #pragma unroll
            for (int j = 0; j < FJ; j++)
                acc[i][j] = __builtin_amdgcn_mfma_f32_16x16x32_bf16(
                    a[i], b[j], acc[i][j], 0, 0, 0);

        if (kt + 1 < nk) {
            __builtin_amdgcn_sched_barrier(0);  // pin reads+MFMA above the sync
            waitv<0>();                         // own stage loads landed (overlapped MFMA)
            __builtin_amdgcn_s_barrier();       // single collective sync per K-step
            cur ^= 1;
        }
    }

    const int erow = (lane >> 4) * 4;
    const int ecol = lane & 15;

    if constexpr (OUT_MODE == 1) {
        #pragma unroll
        for (int i = 0; i < FI; i++) {
            #pragma unroll
            for (int j = 0; j < FJ; j++) {
                const int gcol = tn0 + wn + j * 16 + ecol;
                const float bv = bias ? bias[gcol] : 0.0f;
                const int grow0 = tm0 + wm + i * 16 + erow;
                const int bb = grow0 >> 5, ss = grow0 & 31;
                f32x4 o;
                #pragma unroll
                for (int r = 0; r < 4; r++) o[r] = fmaxf(acc[i][j][r] + bv, 0.0f);
                *(f32x4*)&((float*)C)[(long long)bb * (H_ * S_) + gcol * S_ + ss] = o;
            }
        }
        return;
    } else {
        __syncthreads();
        unsigned short* CTh = (unsigned short*)pool;
        float*          CTf = (float*)pool;

        #pragma unroll
        for (int i = 0; i < FI; i++) {
            #pragma unroll
            for (int j = 0; j < FJ; j++) {
                const int lcol = wn + j * 16 + ecol;
                const int gcol = tn0 + lcol;
                const float bv = bias ? bias[(long long)batch * biasBatch + gcol] : 0.0f;
                float csum = 0.0f;
                #pragma unroll
                for (int r = 0; r < 4; r++) {
                    const int lrow = wm + i * 16 + erow + r;
                    float v = acc[i][j][r] + bv;
                    if (ACC_INIT) v += Cinit[(long long)(tm0 + lrow) * ldci + gcol];
                    if (RELU) v = fmaxf(v, 0.0f);
                    if constexpr (CT_F32) CTf[lrow * CTS + lcol] = v;
                    else                  CTh[lrow * CTS + lcol] = f2bf(v);
                    if constexpr (OUT_MODE == 2) csum += v;
                }
                if constexpr (OUT_MODE == 2) {
                    csum += __shfl_xor(csum, 16, 64);
                    csum += __shfl_xor(csum, 32, 64);
                    if (lane < 16)
                        avgl[((wm >> 4) + i) * BN + wn + j * 16 + lane] = csum;
                }
            }
        }
        __syncthreads();

        if constexpr (CT_F32) {
            constexpr int ITERS = (BM * BN) / 1024;
            #pragma unroll
            for (int it = 0; it < ITERS; it++) {
                const int flat = it * 1024 + tid * 4;
                const int row = flat / BN, col = flat % BN;
                f32x4 vv = *(const f32x4*)&CTf[row * CTS + col];
                if constexpr (OUT_MODE == 3) {
                    if (batch == 0) {
                        short4v p;
                        #pragma unroll
                        for (int c = 0; c < 4; c++) p[c] = (short)f2bf(fmaxf(vv[c], 0.0f));
                        *(short4v*)&((unsigned short*)C2)[(long long)(tm0 + row) * ldc + tn0 + col] = p;
                    } else {
                        *(f32x4*)&((float*)C)[(long long)(batch - 1) * cBatch +
                                              (long long)(tm0 + row) * ldc + tn0 + col] = vv;
                    }
                } else {
                    *(f32x4*)&((float*)C)[(long long)batch * cBatch +
                                          (long long)(tm0 + row) * ldc + tn0 + col] = vv;
                }
            }
        } else {
            constexpr int ITERS = (BM * BN) / 2048;
            #pragma unroll
            for (int it = 0; it < ITERS; it++) {
                const int flat = it * 2048 + tid * 8;
                const int row = flat / BN, col = flat % BN;
                short8 vv = *(const short8*)&CTh[row * CTS + col];
                *(short8*)&((unsigned short*)C)[(long long)batch * cBatch +
                                                (long long)(tm0 + row) * ldc + tn0 + col] = vv;
            }
        }

        if constexpr (OUT_MODE == 2) {
            const int s = tid >> 5, hq = (tid & 31) * 4;
            short4v pk;
            #pragma unroll
            for (int c = 0; c < 4; c++)
                pk[c] = (short)f2bf(avgl[s * BN + hq + c] * (1.0f / 16.0f));
            *(short4v*)&avg_out[((long long)batch * 32 + (tm0 >> 4) + s) * H_ + tn0 + hq] = pk;
        }
    }
}

// Standalone wrapper (guide / att1 / out_conv)
template <int BM, int BN, bool RELU, bool OUT_BF16, int OUT_MODE, bool ACC_INIT>
__global__ __launch_bounds__(256) void mfma_gemm(
    const unsigned short* A, long long aBatch, int lda,
    const unsigned short* Bt, long long bBatch, int ldb,
    const float* bias, long long biasBatch,
    const float* Cinit, int ldci,
    void* C, long long cBatch, int ldc,
    void* C2, unsigned short* avg_out,
    int M, int N, int K)
{
    constexpr bool CT_EN  = (OUT_MODE != 1);
    constexpr bool CT_F32 = CT_EN && ((OUT_MODE == 0 && !OUT_BF16) || OUT_MODE == 3);
    constexpr int  CTS    = CT_F32 ? (BN + 4) : (BN + 8);
    constexpr int  KLOOP_B = 2 * (BM * 32 + BN * 32) * 2;
    constexpr int  CT_B    = CT_EN ? (BM * CTS * (CT_F32 ? 4 : 2)) : 0;
    constexpr int  MAIN_B  = (KLOOP_B > CT_B ? KLOOP_B : CT_B);
    constexpr int  AVG_B   = (OUT_MODE == 2) ? (BM / 16) * BN * 4 : 0;
    __shared__ __align__(16) char pool[MAIN_B + AVG_B];
    gemm_body<BM, BN, RELU, OUT_BF16, OUT_MODE, ACC_INIT>(
        pool, blockIdx.x, gridDim.x,
        A, aBatch, lda, Bt, bBatch, ldb, bias, biasBatch, Cinit, ldci,
        C, cBatch, ldc, C2, avg_out, M, N, K);
}

// Merged launch A: Wcomb (192 blocks) + vis_conv (1024 blocks)
// pool: 128x128 OUT_MODE2 -> max(2*16KB, CT 34816) + AVG 4096 = 38912 -> 4 blk/CU
__global__ __launch_bounds__(256) void wcomb_visconv_kernel(
    const unsigned short* wT_guide, const unsigned short* glob_bf,
    unsigned short* WcombT,
    const unsigned short* visT, const unsigned short* wT_visconv,
    const float* vis_conv_b, unsigned short* vis_seg, unsigned short* avg)
{
    __shared__ __align__(16) char pool[38912];
    if (blockIdx.x < 192) {
        gemm_body<64, 64, false, true, 0, false>(pool, blockIdx.x, 192,
            wT_guide, 0, 1024,
            glob_bf, (long long)H_ * H_, H_,
            nullptr, 0, nullptr, 0,
            WcombT, (long long)H_ * H_, H_, nullptr, nullptr, H_, H_, H_);
    } else {
        gemm_body<128, 128, true, true, 2, false>(pool, blockIdx.x - 192, 1024,
            visT, (long long)V_ * CIN_, CIN_,
            wT_visconv, 0, CIN_,
            vis_conv_b, 0, nullptr, 0,
            vis_seg, (long long)V_ * H_, H_, nullptr, avg, V_, H_, CIN_);
    }
}

// Merged launch B: att2 (512 blocks) + P (768 blocks)
// pool: max(2*16KB, CT 34816) = 34816 -> 4 blk/CU
__global__ __launch_bounds__(256) void att2_p_kernel(
    const unsigned short* vis_seg, const unsigned short* wT_att2,
    const float* att2_b, unsigned short* att2_pre,
    const unsigned short* avg, const unsigned short* WcombT,
    const float* bcomb, float* P, unsigned short* gbuf)
{
    __shared__ __align__(16) char pool[34816];
    if (blockIdx.x < 512) {
        gemm_body<128, 128, false, true, 0, false>(pool, blockIdx.x, 512,
            vis_seg, (long long)V_ * H_, H_,
            wT_att2, 0, H_,
            att2_b, 0, nullptr, 0,
            att2_pre, (long long)V_ * A_, A_, nullptr, nullptr, V_, A_, H_);
    } else {
        gemm_body<64, 64, false, false, 3, false>(pool, blockIdx.x - 512, 768,
            avg, 0, H_,
            WcombT, (long long)H_ * H_, H_,
            bcomb, H_, nullptr, 0,
            P, (long long)BS_ * H_, H_, gbuf, nullptr, BS_, H_, H_);
    }
}

// ---------------------------------------------------------------------------
// tanh-attention + softmax(16) + weighted pool; LAST folds fuse softmax,
// summing the 16 text split-K slabs (+bias) into LDS.
// ---------------------------------------------------------------------------
template <bool LAST>
__global__ __launch_bounds__(256) void fused_att_kernel(
    const float* __restrict__ att1,
    const unsigned short* __restrict__ att2_pre,
    const float* __restrict__ att3_w,
    const float* __restrict__ att3_b,
    const unsigned short* __restrict__ vis_seg,
    float* __restrict__ se_m,
    unsigned short* __restrict__ pse,
    float* __restrict__ att_out, int m,
    const float* __restrict__ se_base,
    const float* __restrict__ text_part,     // [16][64][512] f32 (LAST)
    const float* __restrict__ text_b,        // (LAST)
    unsigned short* __restrict__ vis_new)
{
    const int bs = blockIdx.x, tid = threadIdx.x;
    const int wave = tid >> 6, lane = tid & 63;
    __shared__ float logits[T_], wts[T_];
    __shared__ float part[3][512];
    __shared__ float redf[4][3];
    __shared__ float swf[3];
    __shared__ float tsh[512];

    if constexpr (LAST) {
        const int b = bs >> 5;
        for (int h = tid; h < 512; h += 256) {
            float s = text_b[h];
            #pragma unroll
            for (int p = 0; p < 16; p++)
                s += text_part[p * (64 * 512) + b * 512 + h];
            tsh[h] = s;
        }
    }

    f32x4 a1r = *(const f32x4*)&att1[(long long)bs * A_ + lane * 4];
    f32x4 w3r = *(const f32x4*)&att3_w[lane * 4];

    #pragma unroll
    for (int qq = 0; qq < 4; qq++) {
        const int t = wave * 4 + qq;
        short4v ap = *(const short4v*)&att2_pre[(long long)(bs * T_ + t) * A_ + lane * 4];
        float x = 0.f;
        #pragma unroll
        for (int c = 0; c < 4; c++)
            x += fast_tanhf(a1r[c] + bf2f((unsigned short)ap[c])) * w3r[c];
        #pragma unroll
        for (int off = 32; off > 0; off >>= 1) x += __shfl_down(x, off, 64);
        if (lane == 0) logits[t] = x + att3_b[0];
    }
    __syncthreads();
    if (tid == 0) {
        float mx = logits[0];
        #pragma unroll
        for (int t = 1; t < T_; t++) mx = fmaxf(mx, logits[t]);
        float s = 0.f;
        #pragma unroll
        for (int t = 0; t < T_; t++) { float e = expf(logits[t] - mx); wts[t] = e; s += e; }
        float inv = 1.0f / s;
        #pragma unroll
        for (int t = 0; t < T_; t++) wts[t] *= inv;
    }
    __syncthreads();
    if (tid < T_) att_out[bs * (T_ * SQN_) + tid * SQN_ + m] = wts[tid];

    const int slot = tid & 63, quarter = tid >> 6;
    float s[8] = {};
    #pragma unroll
    for (int tt = 0; tt < 4; tt++) {
        const int t = quarter * 4 + tt;
        short8 vv = *(const short8*)&vis_seg[(long long)(bs * T_ + t) * H_ + slot * 8];
        const float w = wts[t];
        #pragma unroll
        for (int c = 0; c < 8; c++) s[c] += bf2f((unsigned short)vv[c]) * w;
    }
    if (quarter) {
        #pragma unroll
        for (int c = 0; c < 8; c++) part[quarter - 1][slot * 8 + c] = s[c];
    }
    __syncthreads();
    if (quarter == 0) {
        #pragma unroll
        for (int c = 0; c < 8; c++)
            s[c] += part[0][slot * 8 + c] + part[1][slot * 8 + c] + part[2][slot * 8 + c];
    }

    if constexpr (!LAST) {
        if (quarter == 0) {
            f32x4 o0 = {s[0], s[1], s[2], s[3]};
            f32x4 o1 = {s[4], s[5], s[6], s[7]};
            *(f32x4*)&se_m[(long long)bs * H_ + slot * 8] = o0;
            *(f32x4*)&se_m[(long long)bs * H_ + slot * 8 + 4] = o1;
            short8 p;
            #pragma unroll
            for (int c = 0; c < 8; c++) p[c] = (short)f2bf(s[c]);
            *(short8*)&pse[(long long)bs * H_ + slot * 8] = p;
        }
    } else {
        const float* se0 = se_base + (long long)bs * H_;
        const float* se1 = se_base + (long long)BS_ * H_ + (long long)bs * H_;

        float p0 = 0.f, p1 = 0.f, p2 = 0.f;
        {
            const int h2 = tid * 2;
            float t0 = tsh[h2], t1 = tsh[h2 + 1];
            p0 = se0[h2] * t0 + se0[h2 + 1] * t1;
            p1 = se1[h2] * t0 + se1[h2 + 1] * t1;
        }
        if (quarter == 0) {
            #pragma unroll
            for (int c = 0; c < 8; c++) p2 += s[c] * tsh[slot * 8 + c];
        }
        #pragma unroll
        for (int off = 32; off > 0; off >>= 1) {
            p0 += __shfl_down(p0, off, 64);
            p1 += __shfl_down(p1, off, 64);
            p2 += __shfl_down(p2, off, 64);
        }
        if (lane == 0) { redf[wave][0] = p0; redf[wave][1] = p1; redf[wave][2] = p2; }
        __syncthreads();
        if (tid == 0) {
            float d0 = redf[0][0] + redf[1][0] + redf[2][0] + redf[3][0];
            float d1 = redf[0][1] + redf[1][1] + redf[2][1] + redf[3][1];
            float d2 = redf[0][2] + redf[1][2] + redf[2][2] + redf[3][2];
            float mx = fmaxf(d0, fmaxf(d1, d2));
            float e0 = expf(d0 - mx), e1 = expf(d1 - mx), e2 = expf(d2 - mx);
            float inv = 1.0f / (e0 + e1 + e2);
            swf[0] = e0 * inv; swf[1] = e1 * inv; swf[2] = e2 * inv;
        }
        __syncthreads();
        if (quarter == 0) {
            const float w0 = swf[0], w1 = swf[1], w2 = swf[2];
            short8 p;
            #pragma unroll
            for (int c = 0; c < 8; c++) {
                const int h = slot * 8 + c;
                p[c] = (short)f2bf(w0 * se0[h] + w1 * se1[h] + w2 * s[c]);
            }
            *(short8*)&vis_new[(long long)bs * H_ + slot * 8] = p;
        }
    }
}

extern "C" void kernel_launch(void* const* d_in, const int* in_sizes, int n_in,
                              void* d_out, int out_size, void* d_ws, size_t ws_size,
                              hipStream_t stream)
{
    const float* visual       = (const float*)d_in[0];
    const float* text_feature = (const float*)d_in[1];
    const float* vis_conv_w   = (const float*)d_in[2];
    const float* vis_conv_b   = (const float*)d_in[3];
    const float* glob_w       = (const float*)d_in[4];
    const float* glob_b       = (const float*)d_in[5];
    const float* guide_w      = (const float*)d_in[6];
    const float* guide_b      = (const float*)d_in[7];
    const float* att1_w       = (const float*)d_in[8];
    const float* att1_b       = (const float*)d_in[9];
    const float* att2_w       = (const float*)d_in[10];
    const float* att2_b       = (const float*)d_in[11];
    const float* att3_w       = (const float*)d_in[12];
    const float* att3_b       = (const float*)d_in[13];
    const float* out_conv_w   = (const float*)d_in[14];
    const float* out_conv_b   = (const float*)d_in[15];
    const float* text_w       = (const float*)d_in[16];
    const float* text_b       = (const float*)d_in[17];
    float* out = (float*)d_out;
    float* att_out = out + (B_ * H_ * S_);

    char* base = (char*)d_ws;
    unsigned short* visT     = (unsigned short*)(base + 0);
    unsigned short* vis_seg  = (unsigned short*)(base + 33554432);
    unsigned short* att2_pre = (unsigned short*)(base + 67108864);
    float*          se       = (float*)(base + 100663296);
    float*          P        = (float*)(base + 113246208);
    unsigned short* pse      = (unsigned short*)(base + 125829120);
    unsigned short* gbuf     = (unsigned short*)(base + 127926272);
    float*          att1buf  = (float*)(base + 130023424);
    unsigned short* avg      = (unsigned short*)(base + 132120576);
    unsigned short* vis_new  = (unsigned short*)(base + 134348800);
    char*           wbase    = base + 136445952;
    unsigned short* wT_visconv = (unsigned short*)(wbase + 0);
    unsigned short* wT_att2    = (unsigned short*)(wbase + 524288);
    unsigned short* wT_guide   = (unsigned short*)(wbase + 786432);
    unsigned short* wT_att1    = (unsigned short*)(wbase + 1835008);
    unsigned short* wT_out     = (unsigned short*)(wbase + 2097152);
    unsigned short* glob_bf    = (unsigned short*)(wbase + 2621440);
    unsigned short* WcombT     = (unsigned short*)(wbase + 4194304);
    float*          bcomb      = (float*)(wbase + 5767168);
    float*          text_part  = (float*)(wbase + 6291456);   // 2 MB

    // merged prep: visual transpose + weight transposes + glob cast +
    // bcomb + text split-K partials
    prep_kernel<<<dim3(2595), 256, 0, stream>>>(
        visual, vis_conv_w, att2_w, guide_w, att1_w, out_conv_w, glob_w,
        text_feature, text_w, text_b, glob_b, guide_b,
        visT, wT_visconv, wT_att2, wT_guide, wT_att1, wT_out,
        glob_bf, text_part, bcomb);

    // Wcomb MFMA + vis_conv(+avg) in ONE launch
    wcomb_visconv_kernel<<<dim3(192 + 1024), 256, 0, stream>>>(
        wT_guide, glob_bf, WcombT,
        visT, wT_visconv, vis_conv_b, vis_seg, avg);

    // att2_pre + P (both depend only on the previous launch) in ONE launch
    att2_p_kernel<<<dim3(512 + 768), 256, 0, stream>>>(
        vis_seg, wT_att2, att2_b, att2_pre,
        avg, WcombT, bcomb, P, gbuf);

    for (int m = 0; m < SQN_; m++) {
        if (m > 0) {
            mfma_gemm<64, 64, true, true, 0, true><<<dim3(256), 256, 0, stream>>>(
                pse, 0, H_,
                wT_guide + 512, 0, 1024,
                nullptr, 0, P + (long long)(m - 1) * BS_ * H_, H_,
                gbuf, 0, H_, nullptr, nullptr, BS_, H_, H_);
        }
        mfma_gemm<64, 64, false, false, 0, false><<<dim3(128), 256, 0, stream>>>(
            gbuf, 0, H_,
            wT_att1, 0, H_,
            att1_b, 0, nullptr, 0,
            att1buf, 0, A_, nullptr, nullptr, BS_, A_, H_);
        if (m < SQN_ - 1) {
            fused_att_kernel<false><<<dim3(BS_), 256, 0, stream>>>(
                att1buf, att2_pre, att3_w, att3_b, vis_seg,
                se + (long long)m * BS_ * H_, pse, att_out, m,
                nullptr, nullptr, nullptr, nullptr);
        } else {
            fused_att_kernel<true><<<dim3(BS_), 256, 0, stream>>>(
                att1buf, att2_pre, att3_w, att3_b, vis_seg,
                nullptr, nullptr, att_out, m,
                se, text_part, text_b, vis_new);
        }
    }

    // vis_out = relu(vis_new @ out_conv_w + b), transposed store [b][h][s]
    mfma_gemm<64, 64, true, false, 1, false><<<dim3(256), 256, 0, stream>>>(
        vis_new, 0, H_,
        wT_out, 0, H_,
        out_conv_b, 0, nullptr, 0,
        out, 0, 0, nullptr, nullptr, BS_, H_, H_);
}

// Round 8
// 177.015 us; speedup vs baseline: 1.0244x; 1.0244x over previous
//
#include <hip/hip_runtime.h>

#define B_   64
#define CIN_ 512
#define H_   512
#define V_   512
#define S_   32
#define T_   16
#define A_   256
#define SQN_ 3
#define BS_  2048   // B_*S_

typedef float  f32x4  __attribute__((ext_vector_type(4)));
typedef float  f32x2  __attribute__((ext_vector_type(2)));
typedef short  short8 __attribute__((ext_vector_type(8)));
typedef short  short4v __attribute__((ext_vector_type(4)));
typedef unsigned int uint4v __attribute__((ext_vector_type(4)));

__device__ __forceinline__ unsigned short f2bf(float f) {
    union { float f; unsigned int u; } v; v.f = f;
    unsigned int u = v.u;
    unsigned int r = (u + 0x7fffu + ((u >> 16) & 1u)) >> 16;
    return (unsigned short)r;
}
__device__ __forceinline__ float bf2f(unsigned short h) {
    union { unsigned int u; float f; } v; v.u = ((unsigned int)h) << 16;
    return v.f;
}

// fast tanh: (e-1)*rcp(e+1), e=exp(2x) via v_exp_f32; clamp keeps e finite.
__device__ __forceinline__ float fast_tanhf(float x) {
    float cx = fminf(fmaxf(x, -15.0f), 15.0f);
    float e  = __expf(2.0f * cx);
    return (e - 1.0f) * __builtin_amdgcn_rcpf(e + 1.0f);
}

// async global->LDS, 16 B per lane; lds dest = wave-uniform base + lane*16
__device__ __forceinline__ void gload16(const void* g, void* l) {
    __builtin_amdgcn_global_load_lds(
        (const __attribute__((address_space(1))) unsigned int*)g,
        (__attribute__((address_space(3))) unsigned int*)l,
        16, 0, 0);
}

template <int N> __device__ __forceinline__ void waitv() {
    asm volatile("s_waitcnt vmcnt(%0)" :: "n"(N) : "memory");
}

// ---------------------------------------------------------------------------
// prep_kernel (merged, one launch):
//   [0,128)      text split-K f32 partials: nt=id&7 (64n), kc=id>>3 (32k)
//   [128,131)    bcomb: 3 blocks (one per m), coalesced row-walk
//   [131,227)    glob_w f32 -> bf16 cast (8192 floats/block)
//   [227,547)    weight transposes (64x64)
//   [547,2595)   visual transpose-cast, DMA-staged [64k][128v] tiles
// ---------------------------------------------------------------------------
__global__ __launch_bounds__(256) void prep_kernel(
    const float* __restrict__ visual, const float* __restrict__ vis_conv_w,
    const float* __restrict__ att2_w, const float* __restrict__ guide_w,
    const float* __restrict__ att1_w, const float* __restrict__ out_conv_w,
    const float* __restrict__ glob_w, const float* __restrict__ text_feature,
    const float* __restrict__ text_w, const float* __restrict__ text_b,
    const float* __restrict__ glob_b, const float* __restrict__ guide_b,
    unsigned short* __restrict__ visT, unsigned short* __restrict__ wT_visconv,
    unsigned short* __restrict__ wT_att2, unsigned short* __restrict__ wT_guide,
    unsigned short* __restrict__ wT_att1, unsigned short* __restrict__ wT_out,
    unsigned short* __restrict__ glob_bf, float* __restrict__ text_part,
    float* __restrict__ bcomb)
{
    __shared__ __align__(16) char smem[32768];
    const int id  = blockIdx.x;
    const int tid = threadIdx.x;

    if (id < 128) {  // text split-K partial: [64m x 64n] over K=32, f32 exact
        const int nt = id & 7, kc = id >> 3;
        const int n0 = nt * 64, kbase = kc * 32;
        float* Ts = (float*)smem;                 // [64][33]
        float* Ws = (float*)smem + 64 * 33;       // [32][65]
        {
            const int m = tid >> 2, kk = (tid & 3) * 8;
            #pragma unroll
            for (int c = 0; c < 8; c += 4)
                *(f32x4*)&Ts[m * 33 + kk + c] =
                    *(const f32x4*)&text_feature[m * 512 + kbase + kk + c];
            const int kr = tid >> 3, nn = (tid & 7) * 8;
            #pragma unroll
            for (int c = 0; c < 8; c += 4)
                *(f32x4*)&Ws[kr * 65 + nn + c] =
                    *(const f32x4*)&text_w[(long long)(kbase + kr) * 512 + n0 + nn + c];
        }
        __syncthreads();
        const int tm = (tid >> 4) * 4, tn = (tid & 15) * 4;
        float acc[4][4] = {};
        for (int k = 0; k < 32; k++) {
            float a[4], b2[4];
            #pragma unroll
            for (int i = 0; i < 4; i++) a[i] = Ts[(tm + i) * 33 + k];
            #pragma unroll
            for (int j = 0; j < 4; j++) b2[j] = Ws[k * 65 + tn + j];
            #pragma unroll
            for (int i = 0; i < 4; i++)
                #pragma unroll
                for (int j = 0; j < 4; j++) acc[i][j] += a[i] * b2[j];
        }
        #pragma unroll
        for (int i = 0; i < 4; i++)
            #pragma unroll
            for (int j = 0; j < 4; j++)
                text_part[kc * (64 * 512) + (tm + i) * 512 + n0 + tn + j] =
                    acc[i][j] + (kc == 0 ? text_b[n0 + tn + j] : 0.0f);
        return;
    }
    if (id < 131) {  // bcomb[m][j] = glob_b[m] @ guide_w_top[:,j] + guide_b[j]
        const int m = id - 128;
        const int j2 = tid * 2;
        float a0 = guide_b[j2], a1 = guide_b[j2 + 1];
        const float* gb = glob_b + m * 512;
        #pragma unroll 8
        for (int k = 0; k < 512; k++) {
            const float g = gb[k];
            f32x2 w = *(const f32x2*)&guide_w[(long long)k * 512 + j2];  // coalesced
            a0 += g * w[0];
            a1 += g * w[1];
        }
        f32x2 o = {a0, a1};
        *(f32x2*)&bcomb[m * 512 + j2] = o;
        return;
    }
    if (id < 227) {  // glob cast: 8192 floats/block
        const int base = (id - 131) * 8192 + tid * 4;
        #pragma unroll
        for (int it = 0; it < 8; it++) {
            f32x4 v = *(const f32x4*)&glob_w[base + it * 1024];
            short4v o;
            #pragma unroll
            for (int c = 0; c < 4; c++) o[c] = (short)f2bf(v[c]);
            *(short4v*)&glob_bf[base + it * 1024] = o;
        }
        return;
    }

    if (id >= 547) {
        // visual transpose-cast: DMA-staged [64k][128v] tile
        const int q = id - 547;
        const int b = q >> 5, tile = q & 31;
        const int k0 = (tile >> 2) << 6;   // 0..448
        const int v0 = (tile & 3) << 7;    // 0,128,256,384
        const float* src = visual + (long long)b * 262144;
        unsigned short* dst = visT + (long long)b * 262144;
        float* tl = (float*)smem;          // [64][128] linear, 32 KB

        const int wave = tid >> 6, lane = tid & 63;
        #pragma unroll
        for (int i = 0; i < 8; i++) {
            const int r2 = wave * 16 + i * 2;
            gload16(&src[(long long)(k0 + r2 + (lane >> 5)) * 512 + v0 + (lane & 31) * 4],
                    &tl[r2 * 128]);
        }
        __syncthreads();

        const int kl = (tid & 7) * 8;      // 0..56
        const int vb = tid >> 3;           // 0..31
        #pragma unroll
        for (int jv = 0; jv < 4; jv++) {
            const int v = vb + jv * 32;
            short8 o;
            #pragma unroll
            for (int i = 0; i < 8; i++)
                o[i] = (short)f2bf(tl[(kl + i) * 128 + v]);
            *(short8*)&dst[(long long)(v0 + v) * 512 + k0 + kl] = o;
        }
        return;
    }

    // 64x64 transpose-cast (weights): src f32 [Kd][Nd] -> dst bf16 [Nd][Kd]
    const float* src; unsigned short* dst; int Kd, Nd, tile;
    if (id < 291)      { tile = id - 227; src = vis_conv_w; dst = wT_visconv; Kd = 512;  Nd = 512; }
    else if (id < 323) { tile = id - 291; src = att2_w;     dst = wT_att2;    Kd = 512;  Nd = 256; }
    else if (id < 451) { tile = id - 323; src = guide_w;    dst = wT_guide;   Kd = 1024; Nd = 512; }
    else if (id < 483) { tile = id - 451; src = att1_w;     dst = wT_att1;    Kd = 512;  Nd = 256; }
    else               { tile = id - 483; src = out_conv_w; dst = wT_out;     Kd = 512;  Nd = 512; }

    unsigned int* tl = (unsigned int*)smem;  // [64][65]
    const int xw = Nd >> 6;
    const int n0 = (tile % xw) << 6, k0 = (tile / xw) << 6;
    {
        const int r = tid >> 4;
        const int c4 = (tid & 15) * 4;
        #pragma unroll
        for (int j = 0; j < 4; j++) {
            const int row = j * 16 + r;
            f32x4 v = *(const f32x4*)&src[(long long)(k0 + row) * Nd + n0 + c4];
            #pragma unroll
            for (int c2 = 0; c2 < 4; c2++)
                tl[row * 65 + c4 + c2] = f2bf(v[c2]);
        }
    }
    __syncthreads();
    {
        const int v = tid >> 2, cq = (tid & 3) * 16;
        short8 o0, o1;
        #pragma unroll
        for (int j = 0; j < 8; j++) o0[j] = (short)tl[(cq + j) * 65 + v];
        #pragma unroll
        for (int j = 0; j < 8; j++) o1[j] = (short)tl[(cq + 8 + j) * 65 + v];
        *(short8*)&dst[(long long)(n0 + v) * Kd + k0 + cq] = o0;
        *(short8*)&dst[(long long)(n0 + v) * Kd + k0 + cq + 8] = o1;
    }
}

// ---------------------------------------------------------------------------
// GEMM body (r4-proven loop: DEPTH-deep counted-vmcnt staging, two barriers,
// both-sides LDS XOR swizzle). NEW vs r4: for BM=128 the CT epilogue runs as
// TWO 64-row half-passes so the LDS pool shrinks 38912/34816 -> 32768 exactly
// = 5 blocks/CU (163840/32768) instead of 4 -> +25% resident waves on the
// latency-bound merged kernels. avgl lives inside the pool at CT_BYTES.
// ---------------------------------------------------------------------------
template <int BM, int BN, bool RELU, bool OUT_BF16, int OUT_MODE, bool ACC_INIT, int DEPTH>
__device__ __forceinline__ void gemm_body(
    char* pool, int bid, int nwg,
    const unsigned short* __restrict__ A, long long aBatch, int lda,
    const unsigned short* __restrict__ Bt, long long bBatch, int ldb,
    const float* __restrict__ bias, long long biasBatch,
    const float* __restrict__ Cinit, int ldci,
    void* __restrict__ C, long long cBatch, int ldc,
    void* __restrict__ C2, unsigned short* __restrict__ avg_out,
    int M, int N, int K)
{
    constexpr int WM = BM / 2, WN = BN / 2;
    constexpr int FI = WM / 16, FJ = WN / 16;
    constexpr int LOADS = BM / 64 + BN / 64;   // gloads per wave per stage (2 or 4)
    constexpr bool CT_EN  = (OUT_MODE != 1);
    constexpr bool CT_F32 = CT_EN && ((OUT_MODE == 0 && !OUT_BF16) || OUT_MODE == 3);
    constexpr int  CTS    = CT_F32 ? (BN + 4) : (BN + 8);
    constexpr bool HALF_CT = (BM == 128) && CT_EN && !CT_F32;
    constexpr int  KLOOP_B = DEPTH * (BM * 32 + BN * 32) * 2;
    constexpr int  CT_B    = CT_EN ? (BM * CTS * (CT_F32 ? 4 : 2)) : 0;
    constexpr int  CT_BYTES = HALF_CT ? (64 * CTS * 2) : CT_B;
    constexpr int  MAIN_B  = (KLOOP_B > CT_BYTES ? KLOOP_B : CT_BYTES);
    unsigned short* As = (unsigned short*)pool;
    unsigned short* Bs = As + DEPTH * BM * 32;
    float* avgl = (float*)(pool + (HALF_CT ? CT_BYTES : MAIN_B));

    // XCD-chunked bijective swizzle (m204)
    const int q8 = nwg >> 3, r8 = nwg & 7;
    const int xcd = bid & 7, lid = bid >> 3;
    const int logical = (xcd < r8 ? xcd * (q8 + 1)
                                  : r8 * (q8 + 1) + (xcd - r8) * q8) + lid;

    const int ntiles = N / BN;
    const int tilesPerBatch = (M / BM) * ntiles;
    const int batch = logical / tilesPerBatch;
    const int t     = logical % tilesPerBatch;
    const int tm0 = (t / ntiles) * BM;
    const int tn0 = (t % ntiles) * BN;
    const unsigned short* Ab = A + (long long)batch * aBatch;
    const unsigned short* Bb = Bt + (long long)batch * bBatch;

    const int tid  = threadIdx.x;
    const int lane = tid & 63;
    const int wave = tid >> 6;
    const int wm = (wave >> 1) * WM;
    const int wn = (wave & 1) * WN;
    const int lr = lane & 15;
    const int lk = (lane >> 4) * 8;
    const int rsub = lane >> 2;
    // pre-swizzled global 16B slot: (lane&3) ^ ((lane>>3)&3) == (lane&3) ^ ((row>>1)&3)
    const int g8s = ((lane & 3) ^ ((lane >> 3) & 3)) * 8;
    // frag-read elem offset with matching XOR (row key = (lr>>1)&3)
    const int lks = lk ^ (((lr >> 1) & 3) << 3);

    auto stage = [&](int buf, int k0) {
        #pragma unroll
        for (int i = 0; i < BM / 64; i++) {
            const int rbase = wave * (BM / 4) + i * 16;
            gload16(&Ab[(long long)(tm0 + rbase + rsub) * lda + k0 + g8s],
                    &As[buf * (BM * 32) + rbase * 32]);
        }
        #pragma unroll
        for (int i = 0; i < BN / 64; i++) {
            const int rbase = wave * (BN / 4) + i * 16;
            gload16(&Bb[(long long)(tn0 + rbase + rsub) * ldb + k0 + g8s],
                    &Bs[buf * (BN * 32) + rbase * 32]);
        }
    };

    f32x4 acc[FI][FJ] = {};
    const int nk = K >> 5;

    #pragma unroll
    for (int d = 0; d < DEPTH - 1; d++)
        if (d < nk) stage(d, d << 5);

    int cur = 0;
    for (int kt = 0; kt < nk; kt++) {
        if (kt + DEPTH - 1 < nk) {
            const int nb = cur + DEPTH - 1;
            stage(nb >= DEPTH ? nb - DEPTH : nb, (kt + DEPTH - 1) << 5);
        }
        // counted wait: own step-kt loads landed; deeper prefetches stay in
        // flight across the barrier (never vmcnt(0) in the main loop)
        if constexpr (DEPTH == 2) {
            if (kt + 1 < nk) waitv<LOADS>(); else waitv<0>();
        } else {
            if (kt + 2 < nk)      waitv<2 * LOADS>();
            else if (kt + 1 < nk) waitv<LOADS>();
            else                  waitv<0>();
        }
        __builtin_amdgcn_s_barrier();   // publish: every wave's kt-loads landed

        const unsigned short* Ac = As + cur * (BM * 32);
        const unsigned short* Bc = Bs + cur * (BN * 32);
        short8 a[FI], b[FJ];
        #pragma unroll
        for (int i = 0; i < FI; i++)
            a[i] = *(const short8*)&Ac[(wm + i * 16 + lr) * 32 + lks];
        #pragma unroll
        for (int j = 0; j < FJ; j++)
            b[j] = *(const short8*)&Bc[(wn + j * 16 + lr) * 32 + lks];
        #pragma unroll
        for (int i = 0; i < FI; i++)
            #pragma unroll
            for (int j = 0; j < FJ; j++)
                acc[i][j] = __builtin_amdgcn_mfma_f32_16x16x32_bf16(
                    a[i], b[j], acc[i][j], 0, 0, 0);
        __builtin_amdgcn_sched_barrier(0);  // pin reads+MFMA above the barrier
        __builtin_amdgcn_s_barrier();       // all reads of buf 'cur' retired
        cur = (cur + 1 == DEPTH) ? 0 : cur + 1;
    }

    const int erow = (lane >> 4) * 4;
    const int ecol = lane & 15;

    if constexpr (OUT_MODE == 1) {
        #pragma unroll
        for (int i = 0; i < FI; i++) {
            #pragma unroll
            for (int j = 0; j < FJ; j++) {
                const int gcol = tn0 + wn + j * 16 + ecol;
                const float bv = bias ? bias[gcol] : 0.0f;
                const int grow0 = tm0 + wm + i * 16 + erow;
                const int bb = grow0 >> 5, ss = grow0 & 31;
                f32x4 o;
                #pragma unroll
                for (int r = 0; r < 4; r++) o[r] = fmaxf(acc[i][j][r] + bv, 0.0f);
                *(f32x4*)&((float*)C)[(long long)bb * (H_ * S_) + gcol * S_ + ss] = o;
            }
        }
        return;
    } else if constexpr (HALF_CT) {
        // two 64-row half-passes: pool stays at 32768 -> 5 blocks/CU
        __syncthreads();
        unsigned short* CTh = (unsigned short*)pool;
        const int myhalf = (wm >= 64) ? 1 : 0;
        #pragma unroll
        for (int half = 0; half < 2; half++) {
            if (myhalf == half) {
                #pragma unroll
                for (int i = 0; i < FI; i++) {
                    #pragma unroll
                    for (int j = 0; j < FJ; j++) {
                        const int lcol = wn + j * 16 + ecol;
                        const int gcol = tn0 + lcol;
                        const float bv = bias ? bias[(long long)batch * biasBatch + gcol] : 0.0f;
                        float csum = 0.0f;
                        #pragma unroll
                        for (int r = 0; r < 4; r++) {
                            const int lrow = wm + i * 16 + erow + r;
                            float v = acc[i][j][r] + bv;
                            if (ACC_INIT) v += Cinit[(long long)(tm0 + lrow) * ldci + gcol];
                            if (RELU) v = fmaxf(v, 0.0f);
                            CTh[(lrow - half * 64) * CTS + lcol] = f2bf(v);
                            if constexpr (OUT_MODE == 2) csum += v;
                        }
                        if constexpr (OUT_MODE == 2) {
                            csum += __shfl_xor(csum, 16, 64);
                            csum += __shfl_xor(csum, 32, 64);
                            if (lane < 16)
                                avgl[((wm >> 4) + i) * BN + wn + j * 16 + lane] = csum;
                        }
                    }
                }
            }
            __syncthreads();
            constexpr int ITERS = (64 * BN) / 2048;
            #pragma unroll
            for (int it = 0; it < ITERS; it++) {
                const int flat = it * 2048 + tid * 8;
                const int row = flat / BN, col = flat % BN;
                short8 vv = *(const short8*)&CTh[row * CTS + col];
                *(short8*)&((unsigned short*)C)[(long long)batch * cBatch +
                    (long long)(tm0 + half * 64 + row) * ldc + tn0 + col] = vv;
            }
            __syncthreads();
        }
        if constexpr (OUT_MODE == 2) {
            const int s = tid >> 5, hq = (tid & 31) * 4;
            short4v pk;
            #pragma unroll
            for (int c = 0; c < 4; c++)
                pk[c] = (short)f2bf(avgl[s * BN + hq + c] * (1.0f / 16.0f));
            *(short4v*)&avg_out[((long long)batch * 32 + (tm0 >> 4) + s) * H_ + tn0 + hq] = pk;
        }
    } else {
        __syncthreads();
        unsigned short* CTh = (unsigned short*)pool;
        float*          CTf = (float*)pool;

        #pragma unroll
        for (int i = 0; i < FI; i++) {
            #pragma unroll
            for (int j = 0; j < FJ; j++) {
                const int lcol = wn + j * 16 + ecol;
                const int gcol = tn0 + lcol;
                const float bv = bias ? bias[(long long)batch * biasBatch + gcol] : 0.0f;
                float csum = 0.0f;
                #pragma unroll
                for (int r = 0; r < 4; r++) {
                    const int lrow = wm + i * 16 + erow + r;
                    float v = acc[i][j][r] + bv;
                    if (ACC_INIT) v += Cinit[(long long)(tm0 + lrow) * ldci + gcol];
                    if (RELU) v = fmaxf(v, 0.0f);
                    if constexpr (CT_F32) CTf[lrow * CTS + lcol] = v;
                    else                  CTh[lrow * CTS + lcol] = f2bf(v);
                    if constexpr (OUT_MODE == 2) csum += v;
                }
                if constexpr (OUT_MODE == 2) {
                    csum += __shfl_xor(csum, 16, 64);
                    csum += __shfl_xor(csum, 32, 64);
                    if (lane < 16)
                        avgl[((wm >> 4) + i) * BN + wn + j * 16 + lane] = csum;
                }
            }
        }
        __syncthreads();

        if constexpr (CT_F32) {
            constexpr int ITERS = (BM * BN) / 1024;
            #pragma unroll
            for (int it = 0; it < ITERS; it++) {
                const int flat = it * 1024 + tid * 4;
                const int row = flat / BN, col = flat % BN;
                f32x4 vv = *(const f32x4*)&CTf[row * CTS + col];
                if constexpr (OUT_MODE == 3) {
                    if (batch == 0) {
                        short4v p;
                        #pragma unroll
                        for (int c = 0; c < 4; c++) p[c] = (short)f2bf(fmaxf(vv[c], 0.0f));
                        *(short4v*)&((unsigned short*)C2)[(long long)(tm0 + row) * ldc + tn0 + col] = p;
                    } else {
                        *(f32x4*)&((float*)C)[(long long)(batch - 1) * cBatch +
                                              (long long)(tm0 + row) * ldc + tn0 + col] = vv;
                    }
                } else {
                    *(f32x4*)&((float*)C)[(long long)batch * cBatch +
                                          (long long)(tm0 + row) * ldc + tn0 + col] = vv;
                }
            }
        } else {
            constexpr int ITERS = (BM * BN) / 2048;
            #pragma unroll
            for (int it = 0; it < ITERS; it++) {
                const int flat = it * 2048 + tid * 8;
                const int row = flat / BN, col = flat % BN;
                short8 vv = *(const short8*)&CTh[row * CTS + col];
                *(short8*)&((unsigned short*)C)[(long long)batch * cBatch +
                                                (long long)(tm0 + row) * ldc + tn0 + col] = vv;
            }
        }

        if constexpr (OUT_MODE == 2) {
            const int s = tid >> 5, hq = (tid & 31) * 4;
            short4v pk;
            #pragma unroll
            for (int c = 0; c < 4; c++)
                pk[c] = (short)f2bf(avgl[s * BN + hq + c] * (1.0f / 16.0f));
            *(short4v*)&avg_out[((long long)batch * 32 + (tm0 >> 4) + s) * H_ + tn0 + hq] = pk;
        }
    }
}

// Standalone wrapper (guide / att1 / out_conv) — small grids, DEPTH=3
template <int BM, int BN, bool RELU, bool OUT_BF16, int OUT_MODE, bool ACC_INIT, int DEPTH>
__global__ __launch_bounds__(256) void mfma_gemm(
    const unsigned short* A, long long aBatch, int lda,
    const unsigned short* Bt, long long bBatch, int ldb,
    const float* bias, long long biasBatch,
    const float* Cinit, int ldci,
    void* C, long long cBatch, int ldc,
    void* C2, unsigned short* avg_out,
    int M, int N, int K)
{
    constexpr bool CT_EN  = (OUT_MODE != 1);
    constexpr bool CT_F32 = CT_EN && ((OUT_MODE == 0 && !OUT_BF16) || OUT_MODE == 3);
    constexpr int  CTS    = CT_F32 ? (BN + 4) : (BN + 8);
    constexpr bool HALF_CT = (BM == 128) && CT_EN && !CT_F32;
    constexpr int  KLOOP_B = DEPTH * (BM * 32 + BN * 32) * 2;
    constexpr int  CT_B    = CT_EN ? (BM * CTS * (CT_F32 ? 4 : 2)) : 0;
    constexpr int  CT_BYTES = HALF_CT ? (64 * CTS * 2) : CT_B;
    constexpr int  MAIN_B  = (KLOOP_B > CT_BYTES ? KLOOP_B : CT_BYTES);
    constexpr int  AVG_B   = (OUT_MODE == 2 && !HALF_CT) ? (BM / 16) * BN * 4 : 0;
    __shared__ __align__(16) char pool[MAIN_B + AVG_B];
    gemm_body<BM, BN, RELU, OUT_BF16, OUT_MODE, ACC_INIT, DEPTH>(
        pool, blockIdx.x, gridDim.x,
        A, aBatch, lda, Bt, bBatch, ldb, bias, biasBatch, Cinit, ldci,
        C, cBatch, ldc, C2, avg_out, M, N, K);
}

// Merged launch A: Wcomb (192 blocks) + vis_conv (1024 blocks), DEPTH=2
// pool = 32768 exactly -> 5 blocks/CU (163840/32768)
__global__ __launch_bounds__(256) void wcomb_visconv_kernel(
    const unsigned short* wT_guide, const unsigned short* glob_bf,
    unsigned short* WcombT,
    const unsigned short* visT, const unsigned short* wT_visconv,
    const float* vis_conv_b, unsigned short* vis_seg, unsigned short* avg)
{
    __shared__ __align__(16) char pool[32768];
    if (blockIdx.x < 192) {
        gemm_body<64, 64, false, true, 0, false, 2>(pool, blockIdx.x, 192,
            wT_guide, 0, 1024,
            glob_bf, (long long)H_ * H_, H_,
            nullptr, 0, nullptr, 0,
            WcombT, (long long)H_ * H_, H_, nullptr, nullptr, H_, H_, H_);
    } else {
        gemm_body<128, 128, true, true, 2, false, 2>(pool, blockIdx.x - 192, 1024,
            visT, (long long)V_ * CIN_, CIN_,
            wT_visconv, 0, CIN_,
            vis_conv_b, 0, nullptr, 0,
            vis_seg, (long long)V_ * H_, H_, nullptr, avg, V_, H_, CIN_);
    }
}

// Merged launch B: att2 (512 blocks) + P (768 blocks), DEPTH=2
// pool = 32768 -> 5 blocks/CU
__global__ __launch_bounds__(256) void att2_p_kernel(
    const unsigned short* vis_seg, const unsigned short* wT_att2,
    const float* att2_b, unsigned short* att2_pre,
    const unsigned short* avg, const unsigned short* WcombT,
    const float* bcomb, float* P, unsigned short* gbuf)
{
    __shared__ __align__(16) char pool[32768];
    if (blockIdx.x < 512) {
        gemm_body<128, 128, false, true, 0, false, 2>(pool, blockIdx.x, 512,
            vis_seg, (long long)V_ * H_, H_,
            wT_att2, 0, H_,
            att2_b, 0, nullptr, 0,
            att2_pre, (long long)V_ * A_, A_, nullptr, nullptr, V_, A_, H_);
    } else {
        gemm_body<64, 64, false, false, 3, false, 2>(pool, blockIdx.x - 512, 768,
            avg, 0, H_,
            WcombT, (long long)H_ * H_, H_,
            bcomb, H_, nullptr, 0,
            P, (long long)BS_ * H_, H_, gbuf, nullptr, BS_, H_, H_);
    }
}

// ---------------------------------------------------------------------------
// tanh-attention + softmax(16) + weighted pool; LAST folds fuse softmax,
// summing the 16 text split-K slabs (+bias) into LDS.
// ---------------------------------------------------------------------------
template <bool LAST>
__global__ __launch_bounds__(256) void fused_att_kernel(
    const float* __restrict__ att1,
    const unsigned short* __restrict__ att2_pre,
    const float* __restrict__ att3_w,
    const float* __restrict__ att3_b,
    const unsigned short* __restrict__ vis_seg,
    float* __restrict__ se_m,
    unsigned short* __restrict__ pse,
    float* __restrict__ att_out, int m,
    const float* __restrict__ se_base,
    const float* __restrict__ text_part,     // [16][64][512] f32 (LAST)
    const float* __restrict__ text_b,        // (LAST)
    unsigned short* __restrict__ vis_new)
{
    const int bs = blockIdx.x, tid = threadIdx.x;
    const int wave = tid >> 6, lane = tid & 63;
    __shared__ float logits[T_], wts[T_];
    __shared__ float part[3][512];
    __shared__ float redf[4][3];
    __shared__ float swf[3];
    __shared__ float tsh[512];

    if constexpr (LAST) {
        const int b = bs >> 5;
        for (int h = tid; h < 512; h += 256) {
            float s = text_b[h];
            #pragma unroll
            for (int p = 0; p < 16; p++)
                s += text_part[p * (64 * 512) + b * 512 + h];
            tsh[h] = s;
        }
    }

    f32x4 a1r = *(const f32x4*)&att1[(long long)bs * A_ + lane * 4];
    f32x4 w3r = *(const f32x4*)&att3_w[lane * 4];

    #pragma unroll
    for (int qq = 0; qq < 4; qq++) {
        const int t = wave * 4 + qq;
        short4v ap = *(const short4v*)&att2_pre[(long long)(bs * T_ + t) * A_ + lane * 4];
        float x = 0.f;
        #pragma unroll
        for (int c = 0; c < 4; c++)
            x += fast_tanhf(a1r[c] + bf2f((unsigned short)ap[c])) * w3r[c];
        #pragma unroll
        for (int off = 32; off > 0; off >>= 1) x += __shfl_down(x, off, 64);
        if (lane == 0) logits[t] = x + att3_b[0];
    }
    __syncthreads();
    if (tid == 0) {
        float mx = logits[0];
        #pragma unroll
        for (int t = 1; t < T_; t++) mx = fmaxf(mx, logits[t]);
        float s = 0.f;
        #pragma unroll
        for (int t = 0; t < T_; t++) { float e = expf(logits[t] - mx); wts[t] = e; s += e; }
        float inv = 1.0f / s;
        #pragma unroll
        for (int t = 0; t < T_; t++) wts[t] *= inv;
    }
    __syncthreads();
    if (tid < T_) att_out[bs * (T_ * SQN_) + tid * SQN_ + m] = wts[tid];

    const int slot = tid & 63, quarter = tid >> 6;
    float s[8] = {};
    #pragma unroll
    for (int tt = 0; tt < 4; tt++) {
        const int t = quarter * 4 + tt;
        short8 vv = *(const short8*)&vis_seg[(long long)(bs * T_ + t) * H_ + slot * 8];
        const float w = wts[t];
        #pragma unroll
        for (int c = 0; c < 8; c++) s[c] += bf2f((unsigned short)vv[c]) * w;
    }
    if (quarter) {
        #pragma unroll
        for (int c = 0; c < 8; c++) part[quarter - 1][slot * 8 + c] = s[c];
    }
    __syncthreads();
    if (quarter == 0) {
        #pragma unroll
        for (int c = 0; c < 8; c++)
            s[c] += part[0][slot * 8 + c] + part[1][slot * 8 + c] + part[2][slot * 8 + c];
    }

    if constexpr (!LAST) {
        if (quarter == 0) {
            f32x4 o0 = {s[0], s[1], s[2], s[3]};
            f32x4 o1 = {s[4], s[5], s[6], s[7]};
            *(f32x4*)&se_m[(long long)bs * H_ + slot * 8] = o0;
            *(f32x4*)&se_m[(long long)bs * H_ + slot * 8 + 4] = o1;
            short8 p;
            #pragma unroll
            for (int c = 0; c < 8; c++) p[c] = (short)f2bf(s[c]);
            *(short8*)&pse[(long long)bs * H_ + slot * 8] = p;
        }
    } else {
        const float* se0 = se_base + (long long)bs * H_;
        const float* se1 = se_base + (long long)BS_ * H_ + (long long)bs * H_;

        float p0 = 0.f, p1 = 0.f, p2 = 0.f;
        {
            const int h2 = tid * 2;
            float t0 = tsh[h2], t1 = tsh[h2 + 1];
            p0 = se0[h2] * t0 + se0[h2 + 1] * t1;
            p1 = se1[h2] * t0 + se1[h2 + 1] * t1;
        }
        if (quarter == 0) {
            #pragma unroll
            for (int c = 0; c < 8; c++) p2 += s[c] * tsh[slot * 8 + c];
        }
        #pragma unroll
        for (int off = 32; off > 0; off >>= 1) {
            p0 += __shfl_down(p0, off, 64);
            p1 += __shfl_down(p1, off, 64);
            p2 += __shfl_down(p2, off, 64);
        }
        if (lane == 0) { redf[wave][0] = p0; redf[wave][1] = p1; redf[wave][2] = p2; }
        __syncthreads();
        if (tid == 0) {
            float d0 = redf[0][0] + redf[1][0] + redf[2][0] + redf[3][0];
            float d1 = redf[0][1] + redf[1][1] + redf[2][1] + redf[3][1];
            float d2 = redf[0][2] + redf[1][2] + redf[2][2] + redf[3][2];
            float mx = fmaxf(d0, fmaxf(d1, d2));
            float e0 = expf(d0 - mx), e1 = expf(d1 - mx), e2 = expf(d2 - mx);
            float inv = 1.0f / (e0 + e1 + e2);
            swf[0] = e0 * inv; swf[1] = e1 * inv; swf[2] = e2 * inv;
        }
        __syncthreads();
        if (quarter == 0) {
            const float w0 = swf[0], w1 = swf[1], w2 = swf[2];
            short8 p;
            #pragma unroll
            for (int c = 0; c < 8; c++) {
                const int h = slot * 8 + c;
                p[c] = (short)f2bf(w0 * se0[h] + w1 * se1[h] + w2 * s[c]);
            }
            *(short8*)&vis_new[(long long)bs * H_ + slot * 8] = p;
        }
    }
}

extern "C" void kernel_launch(void* const* d_in, const int* in_sizes, int n_in,
                              void* d_out, int out_size, void* d_ws, size_t ws_size,
                              hipStream_t stream)
{
    const float* visual       = (const float*)d_in[0];
    const float* text_feature = (const float*)d_in[1];
    const float* vis_conv_w   = (const float*)d_in[2];
    const float* vis_conv_b   = (const float*)d_in[3];
    const float* glob_w       = (const float*)d_in[4];
    const float* glob_b       = (const float*)d_in[5];
    const float* guide_w      = (const float*)d_in[6];
    const float* guide_b      = (const float*)d_in[7];
    const float* att1_w       = (const float*)d_in[8];
    const float* att1_b       = (const float*)d_in[9];
    const float* att2_w       = (const float*)d_in[10];
    const float* att2_b       = (const float*)d_in[11];
    const float* att3_w       = (const float*)d_in[12];
    const float* att3_b       = (const float*)d_in[13];
    const float* out_conv_w   = (const float*)d_in[14];
    const float* out_conv_b   = (const float*)d_in[15];
    const float* text_w       = (const float*)d_in[16];
    const float* text_b       = (const float*)d_in[17];
    float* out = (float*)d_out;
    float* att_out = out + (B_ * H_ * S_);

    char* base = (char*)d_ws;
    unsigned short* visT     = (unsigned short*)(base + 0);
    unsigned short* vis_seg  = (unsigned short*)(base + 33554432);
    unsigned short* att2_pre = (unsigned short*)(base + 67108864);
    float*          se       = (float*)(base + 100663296);
    float*          P        = (float*)(base + 113246208);
    unsigned short* pse      = (unsigned short*)(base + 125829120);
    unsigned short* gbuf     = (unsigned short*)(base + 127926272);
    float*          att1buf  = (float*)(base + 130023424);
    unsigned short* avg      = (unsigned short*)(base + 132120576);
    unsigned short* vis_new  = (unsigned short*)(base + 134348800);
    char*           wbase    = base + 136445952;
    unsigned short* wT_visconv = (unsigned short*)(wbase + 0);
    unsigned short* wT_att2    = (unsigned short*)(wbase + 524288);
    unsigned short* wT_guide   = (unsigned short*)(wbase + 786432);
    unsigned short* wT_att1    = (unsigned short*)(wbase + 1835008);
    unsigned short* wT_out     = (unsigned short*)(wbase + 2097152);
    unsigned short* glob_bf    = (unsigned short*)(wbase + 2621440);
    unsigned short* WcombT     = (unsigned short*)(wbase + 4194304);
    float*          bcomb      = (float*)(wbase + 5767168);
    float*          text_part  = (float*)(wbase + 6291456);   // 2 MB

    // merged prep: visual transpose + weight transposes + glob cast +
    // bcomb + text split-K partials
    prep_kernel<<<dim3(2595), 256, 0, stream>>>(
        visual, vis_conv_w, att2_w, guide_w, att1_w, out_conv_w, glob_w,
        text_feature, text_w, text_b, glob_b, guide_b,
        visT, wT_visconv, wT_att2, wT_guide, wT_att1, wT_out,
        glob_bf, text_part, bcomb);

    // Wcomb MFMA + vis_conv(+avg) in ONE launch
    wcomb_visconv_kernel<<<dim3(192 + 1024), 256, 0, stream>>>(
        wT_guide, glob_bf, WcombT,
        visT, wT_visconv, vis_conv_b, vis_seg, avg);

    // att2_pre + P (both depend only on the previous launch) in ONE launch
    att2_p_kernel<<<dim3(512 + 768), 256, 0, stream>>>(
        vis_seg, wT_att2, att2_b, att2_pre,
        avg, WcombT, bcomb, P, gbuf);

    for (int m = 0; m < SQN_; m++) {
        if (m > 0) {
            mfma_gemm<64, 64, true, true, 0, true, 3><<<dim3(256), 256, 0, stream>>>(
                pse, 0, H_,
                wT_guide + 512, 0, 1024,
                nullptr, 0, P + (long long)(m - 1) * BS_ * H_, H_,
                gbuf, 0, H_, nullptr, nullptr, BS_, H_, H_);
        }
        mfma_gemm<64, 64, false, false, 0, false, 3><<<dim3(128), 256, 0, stream>>>(
            gbuf, 0, H_,
            wT_att1, 0, H_,
            att1_b, 0, nullptr, 0,
            att1buf, 0, A_, nullptr, nullptr, BS_, A_, H_);
        if (m < SQN_ - 1) {
            fused_att_kernel<false><<<dim3(BS_), 256, 0, stream>>>(
                att1buf, att2_pre, att3_w, att3_b, vis_seg,
                se + (long long)m * BS_ * H_, pse, att_out, m,
                nullptr, nullptr, nullptr, nullptr);
        } else {
            fused_att_kernel<true><<<dim3(BS_), 256, 0, stream>>>(
                att1buf, att2_pre, att3_w, att3_b, vis_seg,
                nullptr, nullptr, att_out, m,
                se, text_part, text_b, vis_new);
        }
    }

    // vis_out = relu(vis_new @ out_conv_w + b), transposed store [b][h][s]
    mfma_gemm<64, 64, true, false, 1, false, 3><<<dim3(256), 256, 0, stream>>>(
        vis_new, 0, H_,
        wT_out, 0, H_,
        out_conv_b, 0, nullptr, 0,
        out, 0, 0, nullptr, nullptr, BS_, H_, H_);
}

// Round 9
// 162.485 us; speedup vs baseline: 1.1160x; 1.0894x over previous
//
#include <hip/hip_runtime.h>

#define B_   64
#define CIN_ 512
#define H_   512
#define V_   512
#define S_   32
#define T_   16
#define A_   256
#define SQN_ 3
#define BS_  2048   // B_*S_

typedef float  f32x4  __attribute__((ext_vector_type(4)));
typedef float  f32x2  __attribute__((ext_vector_type(2)));
typedef short  short8 __attribute__((ext_vector_type(8)));
typedef short  short4v __attribute__((ext_vector_type(4)));
typedef unsigned int uint4v __attribute__((ext_vector_type(4)));

__device__ __forceinline__ unsigned short f2bf(float f) {
    union { float f; unsigned int u; } v; v.f = f;
    unsigned int u = v.u;
    unsigned int r = (u + 0x7fffu + ((u >> 16) & 1u)) >> 16;
    return (unsigned short)r;
}
__device__ __forceinline__ float bf2f(unsigned short h) {
    union { unsigned int u; float f; } v; v.u = ((unsigned int)h) << 16;
    return v.f;
}

// fast tanh: (e-1)*rcp(e+1), e=exp(2x) via v_exp_f32; clamp keeps e finite.
__device__ __forceinline__ float fast_tanhf(float x) {
    float cx = fminf(fmaxf(x, -15.0f), 15.0f);
    float e  = __expf(2.0f * cx);
    return (e - 1.0f) * __builtin_amdgcn_rcpf(e + 1.0f);
}

// async global->LDS, 16 B per lane; lds dest = wave-uniform base + lane*16
__device__ __forceinline__ void gload16(const void* g, void* l) {
    __builtin_amdgcn_global_load_lds(
        (const __attribute__((address_space(1))) unsigned int*)g,
        (__attribute__((address_space(3))) unsigned int*)l,
        16, 0, 0);
}

template <int N> __device__ __forceinline__ void waitv() {
    asm volatile("s_waitcnt vmcnt(%0)" :: "n"(N) : "memory");
}

// ---------------------------------------------------------------------------
// prep_kernel (merged, one launch):
//   [0,128)      text split-K f32 partials: nt=id&7 (64n), kc=id>>3 (32k)
//   [128,131)    bcomb: 3 blocks (one per m), coalesced row-walk
//   [131,227)    glob_w f32 -> bf16 cast (8192 floats/block)
//   [227,547)    weight transposes (64x64)
//   [547,2595)   visual transpose-cast, DMA-staged [64k][128v] tiles
// ---------------------------------------------------------------------------
__global__ __launch_bounds__(256) void prep_kernel(
    const float* __restrict__ visual, const float* __restrict__ vis_conv_w,
    const float* __restrict__ att2_w, const float* __restrict__ guide_w,
    const float* __restrict__ att1_w, const float* __restrict__ out_conv_w,
    const float* __restrict__ glob_w, const float* __restrict__ text_feature,
    const float* __restrict__ text_w, const float* __restrict__ text_b,
    const float* __restrict__ glob_b, const float* __restrict__ guide_b,
    unsigned short* __restrict__ visT, unsigned short* __restrict__ wT_visconv,
    unsigned short* __restrict__ wT_att2, unsigned short* __restrict__ wT_guide,
    unsigned short* __restrict__ wT_att1, unsigned short* __restrict__ wT_out,
    unsigned short* __restrict__ glob_bf, float* __restrict__ text_part,
    float* __restrict__ bcomb)
{
    __shared__ __align__(16) char smem[32768];
    const int id  = blockIdx.x;
    const int tid = threadIdx.x;

    if (id < 128) {  // text split-K partial: [64m x 64n] over K=32, f32 exact
        const int nt = id & 7, kc = id >> 3;
        const int n0 = nt * 64, kbase = kc * 32;
        float* Ts = (float*)smem;                 // [64][33]
        float* Ws = (float*)smem + 64 * 33;       // [32][65]
        {
            const int m = tid >> 2, kk = (tid & 3) * 8;
            #pragma unroll
            for (int c = 0; c < 8; c += 4)
                *(f32x4*)&Ts[m * 33 + kk + c] =
                    *(const f32x4*)&text_feature[m * 512 + kbase + kk + c];
            const int kr = tid >> 3, nn = (tid & 7) * 8;
            #pragma unroll
            for (int c = 0; c < 8; c += 4)
                *(f32x4*)&Ws[kr * 65 + nn + c] =
                    *(const f32x4*)&text_w[(long long)(kbase + kr) * 512 + n0 + nn + c];
        }
        __syncthreads();
        const int tm = (tid >> 4) * 4, tn = (tid & 15) * 4;
        float acc[4][4] = {};
        for (int k = 0; k < 32; k++) {
            float a[4], b2[4];
            #pragma unroll
            for (int i = 0; i < 4; i++) a[i] = Ts[(tm + i) * 33 + k];
            #pragma unroll
            for (int j = 0; j < 4; j++) b2[j] = Ws[k * 65 + tn + j];
            #pragma unroll
            for (int i = 0; i < 4; i++)
                #pragma unroll
                for (int j = 0; j < 4; j++) acc[i][j] += a[i] * b2[j];
        }
        #pragma unroll
        for (int i = 0; i < 4; i++)
            #pragma unroll
            for (int j = 0; j < 4; j++)
                text_part[kc * (64 * 512) + (tm + i) * 512 + n0 + tn + j] =
                    acc[i][j] + (kc == 0 ? text_b[n0 + tn + j] : 0.0f);
        return;
    }
    if (id < 131) {  // bcomb[m][j] = glob_b[m] @ guide_w_top[:,j] + guide_b[j]
        const int m = id - 128;
        const int j2 = tid * 2;
        float a0 = guide_b[j2], a1 = guide_b[j2 + 1];
        const float* gb = glob_b + m * 512;
        #pragma unroll 8
        for (int k = 0; k < 512; k++) {
            const float g = gb[k];
            f32x2 w = *(const f32x2*)&guide_w[(long long)k * 512 + j2];  // coalesced
            a0 += g * w[0];
            a1 += g * w[1];
        }
        f32x2 o = {a0, a1};
        *(f32x2*)&bcomb[m * 512 + j2] = o;
        return;
    }
    if (id < 227) {  // glob cast: 8192 floats/block
        const int base = (id - 131) * 8192 + tid * 4;
        #pragma unroll
        for (int it = 0; it < 8; it++) {
            f32x4 v = *(const f32x4*)&glob_w[base + it * 1024];
            short4v o;
            #pragma unroll
            for (int c = 0; c < 4; c++) o[c] = (short)f2bf(v[c]);
            *(short4v*)&glob_bf[base + it * 1024] = o;
        }
        return;
    }

    if (id >= 547) {
        // visual transpose-cast: DMA-staged [64k][128v] tile
        const int q = id - 547;
        const int b = q >> 5, tile = q & 31;
        const int k0 = (tile >> 2) << 6;   // 0..448
        const int v0 = (tile & 3) << 7;    // 0,128,256,384
        const float* src = visual + (long long)b * 262144;
        unsigned short* dst = visT + (long long)b * 262144;
        float* tl = (float*)smem;          // [64][128] linear, 32 KB

        const int wave = tid >> 6, lane = tid & 63;
        #pragma unroll
        for (int i = 0; i < 8; i++) {
            const int r2 = wave * 16 + i * 2;
            gload16(&src[(long long)(k0 + r2 + (lane >> 5)) * 512 + v0 + (lane & 31) * 4],
                    &tl[r2 * 128]);
        }
        __syncthreads();

        const int kl = (tid & 7) * 8;      // 0..56
        const int vb = tid >> 3;           // 0..31
        #pragma unroll
        for (int jv = 0; jv < 4; jv++) {
            const int v = vb + jv * 32;
            short8 o;
            #pragma unroll
            for (int i = 0; i < 8; i++)
                o[i] = (short)f2bf(tl[(kl + i) * 128 + v]);
            *(short8*)&dst[(long long)(v0 + v) * 512 + k0 + kl] = o;
        }
        return;
    }

    // 64x64 transpose-cast (weights): src f32 [Kd][Nd] -> dst bf16 [Nd][Kd]
    const float* src; unsigned short* dst; int Kd, Nd, tile;
    if (id < 291)      { tile = id - 227; src = vis_conv_w; dst = wT_visconv; Kd = 512;  Nd = 512; }
    else if (id < 323) { tile = id - 291; src = att2_w;     dst = wT_att2;    Kd = 512;  Nd = 256; }
    else if (id < 451) { tile = id - 323; src = guide_w;    dst = wT_guide;   Kd = 1024; Nd = 512; }
    else if (id < 483) { tile = id - 451; src = att1_w;     dst = wT_att1;    Kd = 512;  Nd = 256; }
    else               { tile = id - 483; src = out_conv_w; dst = wT_out;     Kd = 512;  Nd = 512; }

    unsigned int* tl = (unsigned int*)smem;  // [64][65]
    const int xw = Nd >> 6;
    const int n0 = (tile % xw) << 6, k0 = (tile / xw) << 6;
    {
        const int r = tid >> 4;
        const int c4 = (tid & 15) * 4;
        #pragma unroll
        for (int j = 0; j < 4; j++) {
            const int row = j * 16 + r;
            f32x4 v = *(const f32x4*)&src[(long long)(k0 + row) * Nd + n0 + c4];
            #pragma unroll
            for (int c2 = 0; c2 < 4; c2++)
                tl[row * 65 + c4 + c2] = f2bf(v[c2]);
        }
    }
    __syncthreads();
    {
        const int v = tid >> 2, cq = (tid & 3) * 16;
        short8 o0, o1;
        #pragma unroll
        for (int j = 0; j < 8; j++) o0[j] = (short)tl[(cq + j) * 65 + v];
        #pragma unroll
        for (int j = 0; j < 8; j++) o1[j] = (short)tl[(cq + 8 + j) * 65 + v];
        *(short8*)&dst[(long long)(n0 + v) * Kd + k0 + cq] = o0;
        *(short8*)&dst[(long long)(n0 + v) * Kd + k0 + cq + 8] = o1;
    }
}

// ---------------------------------------------------------------------------
// GEMM body (r4-proven): DEPTH-deep counted-vmcnt staging (never vmcnt(0) in
// the main loop), two barriers per K-step, both-sides LDS XOR swizzle.
// DEPTH=2 for merged big kernels (4 blocks/CU), DEPTH=3 for small grids.
// ---------------------------------------------------------------------------
template <int BM, int BN, bool RELU, bool OUT_BF16, int OUT_MODE, bool ACC_INIT, int DEPTH>
__device__ __forceinline__ void gemm_body(
    char* pool, int bid, int nwg,
    const unsigned short* __restrict__ A, long long aBatch, int lda,
    const unsigned short* __restrict__ Bt, long long bBatch, int ldb,
    const float* __restrict__ bias, long long biasBatch,
    const float* __restrict__ Cinit, int ldci,
    void* __restrict__ C, long long cBatch, int ldc,
    void* __restrict__ C2, unsigned short* __restrict__ avg_out,
    int M, int N, int K)
{
    constexpr int WM = BM / 2, WN = BN / 2;
    constexpr int FI = WM / 16, FJ = WN / 16;
    constexpr int LOADS = BM / 64 + BN / 64;   // gloads per wave per stage (2 or 4)
    constexpr bool CT_EN  = (OUT_MODE != 1);
    constexpr bool CT_F32 = CT_EN && ((OUT_MODE == 0 && !OUT_BF16) || OUT_MODE == 3);
    constexpr int  CTS    = CT_F32 ? (BN + 4) : (BN + 8);
    constexpr int  KLOOP_B = DEPTH * (BM * 32 + BN * 32) * 2;
    constexpr int  CT_B    = CT_EN ? (BM * CTS * (CT_F32 ? 4 : 2)) : 0;
    constexpr int  MAIN_B  = (KLOOP_B > CT_B ? KLOOP_B : CT_B);
    unsigned short* As = (unsigned short*)pool;
    unsigned short* Bs = As + DEPTH * BM * 32;
    float* avgl = (float*)(pool + MAIN_B);

    // XCD-chunked bijective swizzle (m204)
    const int q8 = nwg >> 3, r8 = nwg & 7;
    const int xcd = bid & 7, lid = bid >> 3;
    const int logical = (xcd < r8 ? xcd * (q8 + 1)
                                  : r8 * (q8 + 1) + (xcd - r8) * q8) + lid;

    const int ntiles = N / BN;
    const int tilesPerBatch = (M / BM) * ntiles;
    const int batch = logical / tilesPerBatch;
    const int t     = logical % tilesPerBatch;
    const int tm0 = (t / ntiles) * BM;
    const int tn0 = (t % ntiles) * BN;
    const unsigned short* Ab = A + (long long)batch * aBatch;
    const unsigned short* Bb = Bt + (long long)batch * bBatch;

    const int tid  = threadIdx.x;
    const int lane = tid & 63;
    const int wave = tid >> 6;
    const int wm = (wave >> 1) * WM;
    const int wn = (wave & 1) * WN;
    const int lr = lane & 15;
    const int lk = (lane >> 4) * 8;
    const int rsub = lane >> 2;
    // pre-swizzled global 16B slot: (lane&3) ^ ((lane>>3)&3) == (lane&3) ^ ((row>>1)&3)
    const int g8s = ((lane & 3) ^ ((lane >> 3) & 3)) * 8;
    // frag-read elem offset with matching XOR (row key = (lr>>1)&3)
    const int lks = lk ^ (((lr >> 1) & 3) << 3);

    auto stage = [&](int buf, int k0) {
        #pragma unroll
        for (int i = 0; i < BM / 64; i++) {
            const int rbase = wave * (BM / 4) + i * 16;
            gload16(&Ab[(long long)(tm0 + rbase + rsub) * lda + k0 + g8s],
                    &As[buf * (BM * 32) + rbase * 32]);
        }
        #pragma unroll
        for (int i = 0; i < BN / 64; i++) {
            const int rbase = wave * (BN / 4) + i * 16;
            gload16(&Bb[(long long)(tn0 + rbase + rsub) * ldb + k0 + g8s],
                    &Bs[buf * (BN * 32) + rbase * 32]);
        }
    };

    f32x4 acc[FI][FJ] = {};
    const int nk = K >> 5;

    #pragma unroll
    for (int d = 0; d < DEPTH - 1; d++)
        if (d < nk) stage(d, d << 5);

    int cur = 0;
    for (int kt = 0; kt < nk; kt++) {
        if (kt + DEPTH - 1 < nk) {
            const int nb = cur + DEPTH - 1;
            stage(nb >= DEPTH ? nb - DEPTH : nb, (kt + DEPTH - 1) << 5);
        }
        // counted wait: own step-kt loads landed; deeper prefetches stay in
        // flight across the barrier (never vmcnt(0) in the main loop)
        if constexpr (DEPTH == 2) {
            if (kt + 1 < nk) waitv<LOADS>(); else waitv<0>();
        } else {
            if (kt + 2 < nk)      waitv<2 * LOADS>();
            else if (kt + 1 < nk) waitv<LOADS>();
            else                  waitv<0>();
        }
        __builtin_amdgcn_s_barrier();   // publish: every wave's kt-loads landed

        const unsigned short* Ac = As + cur * (BM * 32);
        const unsigned short* Bc = Bs + cur * (BN * 32);
        short8 a[FI], b[FJ];
        #pragma unroll
        for (int i = 0; i < FI; i++)
            a[i] = *(const short8*)&Ac[(wm + i * 16 + lr) * 32 + lks];
        #pragma unroll
        for (int j = 0; j < FJ; j++)
            b[j] = *(const short8*)&Bc[(wn + j * 16 + lr) * 32 + lks];
        #pragma unroll
        for (int i = 0; i < FI; i++)
            #pragma unroll
            for (int j = 0; j < FJ; j++)
                acc[i][j] = __builtin_amdgcn_mfma_f32_16x16x32_bf16(
                    a[i], b[j], acc[i][j], 0, 0, 0);
        __builtin_amdgcn_sched_barrier(0);  // pin reads+MFMA above the barrier
        __builtin_amdgcn_s_barrier();       // all reads of buf 'cur' retired
        cur = (cur + 1 == DEPTH) ? 0 : cur + 1;
    }

    const int erow = (lane >> 4) * 4;
    const int ecol = lane & 15;

    if constexpr (OUT_MODE == 1) {
        #pragma unroll
        for (int i = 0; i < FI; i++) {
            #pragma unroll
            for (int j = 0; j < FJ; j++) {
                const int gcol = tn0 + wn + j * 16 + ecol;
                const float bv = bias ? bias[gcol] : 0.0f;
                const int grow0 = tm0 + wm + i * 16 + erow;
                const int bb = grow0 >> 5, ss = grow0 & 31;
                f32x4 o;
                #pragma unroll
                for (int r = 0; r < 4; r++) o[r] = fmaxf(acc[i][j][r] + bv, 0.0f);
                *(f32x4*)&((float*)C)[(long long)bb * (H_ * S_) + gcol * S_ + ss] = o;
            }
        }
        return;
    } else {
        __syncthreads();
        unsigned short* CTh = (unsigned short*)pool;
        float*          CTf = (float*)pool;

        #pragma unroll
        for (int i = 0; i < FI; i++) {
            #pragma unroll
            for (int j = 0; j < FJ; j++) {
                const int lcol = wn + j * 16 + ecol;
                const int gcol = tn0 + lcol;
                const float bv = bias ? bias[(long long)batch * biasBatch + gcol] : 0.0f;
                float csum = 0.0f;
                #pragma unroll
                for (int r = 0; r < 4; r++) {
                    const int lrow = wm + i * 16 + erow + r;
                    float v = acc[i][j][r] + bv;
                    if (ACC_INIT) v += Cinit[(long long)(tm0 + lrow) * ldci + gcol];
                    if (RELU) v = fmaxf(v, 0.0f);
                    if constexpr (CT_F32) CTf[lrow * CTS + lcol] = v;
                    else                  CTh[lrow * CTS + lcol] = f2bf(v);
                    if constexpr (OUT_MODE == 2) csum += v;
                }
                if constexpr (OUT_MODE == 2) {
                    csum += __shfl_xor(csum, 16, 64);
                    csum += __shfl_xor(csum, 32, 64);
                    if (lane < 16)
                        avgl[((wm >> 4) + i) * BN + wn + j * 16 + lane] = csum;
                }
            }
        }
        __syncthreads();

        if constexpr (CT_F32) {
            constexpr int ITERS = (BM * BN) / 1024;
            #pragma unroll
            for (int it = 0; it < ITERS; it++) {
                const int flat = it * 1024 + tid * 4;
                const int row = flat / BN, col = flat % BN;
                f32x4 vv = *(const f32x4*)&CTf[row * CTS + col];
                if constexpr (OUT_MODE == 3) {
                    if (batch == 0) {
                        short4v p;
                        #pragma unroll
                        for (int c = 0; c < 4; c++) p[c] = (short)f2bf(fmaxf(vv[c], 0.0f));
                        *(short4v*)&((unsigned short*)C2)[(long long)(tm0 + row) * ldc + tn0 + col] = p;
                    } else {
                        *(f32x4*)&((float*)C)[(long long)(batch - 1) * cBatch +
                                              (long long)(tm0 + row) * ldc + tn0 + col] = vv;
                    }
                } else {
                    *(f32x4*)&((float*)C)[(long long)batch * cBatch +
                                          (long long)(tm0 + row) * ldc + tn0 + col] = vv;
                }
            }
        } else {
            constexpr int ITERS = (BM * BN) / 2048;
            #pragma unroll
            for (int it = 0; it < ITERS; it++) {
                const int flat = it * 2048 + tid * 8;
                const int row = flat / BN, col = flat % BN;
                short8 vv = *(const short8*)&CTh[row * CTS + col];
                *(short8*)&((unsigned short*)C)[(long long)batch * cBatch +
                                                (long long)(tm0 + row) * ldc + tn0 + col] = vv;
            }
        }

        if constexpr (OUT_MODE == 2) {
            const int s = tid >> 5, hq = (tid & 31) * 4;
            short4v pk;
            #pragma unroll
            for (int c = 0; c < 4; c++)
                pk[c] = (short)f2bf(avgl[s * BN + hq + c] * (1.0f / 16.0f));
            *(short4v*)&avg_out[((long long)batch * 32 + (tm0 >> 4) + s) * H_ + tn0 + hq] = pk;
        }
    }
}

// Standalone wrapper (guide / att1 / out_conv) — small grids, DEPTH=3
template <int BM, int BN, bool RELU, bool OUT_BF16, int OUT_MODE, bool ACC_INIT, int DEPTH>
__global__ __launch_bounds__(256) void mfma_gemm(
    const unsigned short* A, long long aBatch, int lda,
    const unsigned short* Bt, long long bBatch, int ldb,
    const float* bias, long long biasBatch,
    const float* Cinit, int ldci,
    void* C, long long cBatch, int ldc,
    void* C2, unsigned short* avg_out,
    int M, int N, int K)
{
    constexpr bool CT_EN  = (OUT_MODE != 1);
    constexpr bool CT_F32 = CT_EN && ((OUT_MODE == 0 && !OUT_BF16) || OUT_MODE == 3);
    constexpr int  CTS    = CT_F32 ? (BN + 4) : (BN + 8);
    constexpr int  KLOOP_B = DEPTH * (BM * 32 + BN * 32) * 2;
    constexpr int  CT_B    = CT_EN ? (BM * CTS * (CT_F32 ? 4 : 2)) : 0;
    constexpr int  MAIN_B  = (KLOOP_B > CT_B ? KLOOP_B : CT_B);
    constexpr int  AVG_B   = (OUT_MODE == 2) ? (BM / 16) * BN * 4 : 0;
    __shared__ __align__(16) char pool[MAIN_B + AVG_B];
    gemm_body<BM, BN, RELU, OUT_BF16, OUT_MODE, ACC_INIT, DEPTH>(
        pool, blockIdx.x, gridDim.x,
        A, aBatch, lda, Bt, bBatch, ldb, bias, biasBatch, Cinit, ldci,
        C, cBatch, ldc, C2, avg_out, M, N, K);
}

// Merged launch A: Wcomb (192) + vis_conv (1024) + text_att sum (64), DEPTH=2
// pool: 128x128 OUT_MODE2 -> max(2*16KB, CT 34816) + AVG 4096 = 38912 -> 4 blk/CU
__global__ __launch_bounds__(256) void wcomb_visconv_kernel(
    const unsigned short* wT_guide, const unsigned short* glob_bf,
    unsigned short* WcombT,
    const unsigned short* visT, const unsigned short* wT_visconv,
    const float* vis_conv_b, unsigned short* vis_seg, unsigned short* avg,
    const float* __restrict__ text_part, const float* __restrict__ text_b,
    float* __restrict__ text_att)
{
    __shared__ __align__(16) char pool[38912];
    if (blockIdx.x < 192) {
        gemm_body<64, 64, false, true, 0, false, 2>(pool, blockIdx.x, 192,
            wT_guide, 0, 1024,
            glob_bf, (long long)H_ * H_, H_,
            nullptr, 0, nullptr, 0,
            WcombT, (long long)H_ * H_, H_, nullptr, nullptr, H_, H_, H_);
    } else if (blockIdx.x < 1216) {
        gemm_body<128, 128, true, true, 2, false, 2>(pool, blockIdx.x - 192, 1024,
            visT, (long long)V_ * CIN_, CIN_,
            wT_visconv, 0, CIN_,
            vis_conv_b, 0, nullptr, 0,
            vis_seg, (long long)V_ * H_, H_, nullptr, avg, V_, H_, CIN_);
    } else {
        // text_att[b][h] = text_b[h] + sum_p text_part[p][b][h]  (64 blocks)
        const int b = blockIdx.x - 1216;
        const int tid = threadIdx.x;
        #pragma unroll
        for (int hh = 0; hh < 2; hh++) {
            const int h = tid + hh * 256;
            float s = text_b[h];
            #pragma unroll
            for (int p = 0; p < 16; p++)
                s += text_part[p * (64 * 512) + b * 512 + h];
            text_att[b * 512 + h] = s;
        }
    }
}

// Merged launch B: att2 (512 blocks) + P (768 blocks), DEPTH=2
// pool: max(2*16KB, CT 34816) = 34816 -> 4 blk/CU
__global__ __launch_bounds__(256) void att2_p_kernel(
    const unsigned short* vis_seg, const unsigned short* wT_att2,
    const float* att2_b, unsigned short* att2_pre,
    const unsigned short* avg, const unsigned short* WcombT,
    const float* bcomb, float* P, unsigned short* gbuf)
{
    __shared__ __align__(16) char pool[34816];
    if (blockIdx.x < 512) {
        gemm_body<128, 128, false, true, 0, false, 2>(pool, blockIdx.x, 512,
            vis_seg, (long long)V_ * H_, H_,
            wT_att2, 0, H_,
            att2_b, 0, nullptr, 0,
            att2_pre, (long long)V_ * A_, A_, nullptr, nullptr, V_, A_, H_);
    } else {
        gemm_body<64, 64, false, false, 3, false, 2>(pool, blockIdx.x - 512, 768,
            avg, 0, H_,
            WcombT, (long long)H_ * H_, H_,
            bcomb, H_, nullptr, 0,
            P, (long long)BS_ * H_, H_, gbuf, nullptr, BS_, H_, H_);
    }
}

// ---------------------------------------------------------------------------
// tanh-attention + softmax(16) + weighted pool; LAST folds fuse softmax.
// text_att is precomputed (launch A) — LAST blocks just load 512 floats.
// ---------------------------------------------------------------------------
template <bool LAST>
__global__ __launch_bounds__(256) void fused_att_kernel(
    const float* __restrict__ att1,
    const unsigned short* __restrict__ att2_pre,
    const float* __restrict__ att3_w,
    const float* __restrict__ att3_b,
    const unsigned short* __restrict__ vis_seg,
    float* __restrict__ se_m,
    unsigned short* __restrict__ pse,
    float* __restrict__ att_out, int m,
    const float* __restrict__ se_base,
    const float* __restrict__ text_att,      // [64][512] f32 (LAST)
    unsigned short* __restrict__ vis_new)
{
    const int bs = blockIdx.x, tid = threadIdx.x;
    const int wave = tid >> 6, lane = tid & 63;
    __shared__ float logits[T_], wts[T_];
    __shared__ float part[3][512];
    __shared__ float redf[4][3];
    __shared__ float swf[3];
    __shared__ float tsh[512];

    if constexpr (LAST) {
        const int b = bs >> 5;
        #pragma unroll
        for (int hh = 0; hh < 2; hh++) {
            const int h = tid + hh * 256;
            tsh[h] = text_att[b * 512 + h];
        }
    }

    f32x4 a1r = *(const f32x4*)&att1[(long long)bs * A_ + lane * 4];
    f32x4 w3r = *(const f32x4*)&att3_w[lane * 4];

    #pragma unroll
    for (int qq = 0; qq < 4; qq++) {
        const int t = wave * 4 + qq;
        short4v ap = *(const short4v*)&att2_pre[(long long)(bs * T_ + t) * A_ + lane * 4];
        float x = 0.f;
        #pragma unroll
        for (int c = 0; c < 4; c++)
            x += fast_tanhf(a1r[c] + bf2f((unsigned short)ap[c])) * w3r[c];
        #pragma unroll
        for (int off = 32; off > 0; off >>= 1) x += __shfl_down(x, off, 64);
        if (lane == 0) logits[t] = x + att3_b[0];
    }
    __syncthreads();
    if (tid == 0) {
        float mx = logits[0];
        #pragma unroll
        for (int t = 1; t < T_; t++) mx = fmaxf(mx, logits[t]);
        float s = 0.f;
        #pragma unroll
        for (int t = 0; t < T_; t++) { float e = expf(logits[t] - mx); wts[t] = e; s += e; }
        float inv = 1.0f / s;
        #pragma unroll
        for (int t = 0; t < T_; t++) wts[t] *= inv;
    }
    __syncthreads();
    if (tid < T_) att_out[bs * (T_ * SQN_) + tid * SQN_ + m] = wts[tid];

    const int slot = tid & 63, quarter = tid >> 6;
    float s[8] = {};
    #pragma unroll
    for (int tt = 0; tt < 4; tt++) {
        const int t = quarter * 4 + tt;
        short8 vv = *(const short8*)&vis_seg[(long long)(bs * T_ + t) * H_ + slot * 8];
        const float w = wts[t];
        #pragma unroll
        for (int c = 0; c < 8; c++) s[c] += bf2f((unsigned short)vv[c]) * w;
    }
    if (quarter) {
        #pragma unroll
        for (int c = 0; c < 8; c++) part[quarter - 1][slot * 8 + c] = s[c];
    }
    __syncthreads();
    if (quarter == 0) {
        #pragma unroll
        for (int c = 0; c < 8; c++)
            s[c] += part[0][slot * 8 + c] + part[1][slot * 8 + c] + part[2][slot * 8 + c];
    }

    if constexpr (!LAST) {
        if (quarter == 0) {
            f32x4 o0 = {s[0], s[1], s[2], s[3]};
            f32x4 o1 = {s[4], s[5], s[6], s[7]};
            *(f32x4*)&se_m[(long long)bs * H_ + slot * 8] = o0;
            *(f32x4*)&se_m[(long long)bs * H_ + slot * 8 + 4] = o1;
            short8 p;
            #pragma unroll
            for (int c = 0; c < 8; c++) p[c] = (short)f2bf(s[c]);
            *(short8*)&pse[(long long)bs * H_ + slot * 8] = p;
        }
    } else {
        const float* se0 = se_base + (long long)bs * H_;
        const float* se1 = se_base + (long long)BS_ * H_ + (long long)bs * H_;

        float p0 = 0.f, p1 = 0.f, p2 = 0.f;
        {
            const int h2 = tid * 2;
            float t0 = tsh[h2], t1 = tsh[h2 + 1];
            p0 = se0[h2] * t0 + se0[h2 + 1] * t1;
            p1 = se1[h2] * t0 + se1[h2 + 1] * t1;
        }
        if (quarter == 0) {
            #pragma unroll
            for (int c = 0; c < 8; c++) p2 += s[c] * tsh[slot * 8 + c];
        }
        #pragma unroll
        for (int off = 32; off > 0; off >>= 1) {
            p0 += __shfl_down(p0, off, 64);
            p1 += __shfl_down(p1, off, 64);
            p2 += __shfl_down(p2, off, 64);
        }
        if (lane == 0) { redf[wave][0] = p0; redf[wave][1] = p1; redf[wave][2] = p2; }
        __syncthreads();
        if (tid == 0) {
            float d0 = redf[0][0] + redf[1][0] + redf[2][0] + redf[3][0];
            float d1 = redf[0][1] + redf[1][1] + redf[2][1] + redf[3][1];
            float d2 = redf[0][2] + redf[1][2] + redf[2][2] + redf[3][2];
            float mx = fmaxf(d0, fmaxf(d1, d2));
            float e0 = expf(d0 - mx), e1 = expf(d1 - mx), e2 = expf(d2 - mx);
            float inv = 1.0f / (e0 + e1 + e2);
            swf[0] = e0 * inv; swf[1] = e1 * inv; swf[2] = e2 * inv;
        }
        __syncthreads();
        if (quarter == 0) {
            const float w0 = swf[0], w1 = swf[1], w2 = swf[2];
            short8 p;
            #pragma unroll
            for (int c = 0; c < 8; c++) {
                const int h = slot * 8 + c;
                p[c] = (short)f2bf(w0 * se0[h] + w1 * se1[h] + w2 * s[c]);
            }
            *(short8*)&vis_new[(long long)bs * H_ + slot * 8] = p;
        }
    }
}

extern "C" void kernel_launch(void* const* d_in, const int* in_sizes, int n_in,
                              void* d_out, int out_size, void* d_ws, size_t ws_size,
                              hipStream_t stream)
{
    const float* visual       = (const float*)d_in[0];
    const float* text_feature = (const float*)d_in[1];
    const float* vis_conv_w   = (const float*)d_in[2];
    const float* vis_conv_b   = (const float*)d_in[3];
    const float* glob_w       = (const float*)d_in[4];
    const float* glob_b       = (const float*)d_in[5];
    const float* guide_w      = (const float*)d_in[6];
    const float* guide_b      = (const float*)d_in[7];
    const float* att1_w       = (const float*)d_in[8];
    const float* att1_b       = (const float*)d_in[9];
    const float* att2_w       = (const float*)d_in[10];
    const float* att2_b       = (const float*)d_in[11];
    const float* att3_w       = (const float*)d_in[12];
    const float* att3_b       = (const float*)d_in[13];
    const float* out_conv_w   = (const float*)d_in[14];
    const float* out_conv_b   = (const float*)d_in[15];
    const float* text_w       = (const float*)d_in[16];
    const float* text_b       = (const float*)d_in[17];
    float* out = (float*)d_out;
    float* att_out = out + (B_ * H_ * S_);

    char* base = (char*)d_ws;
    unsigned short* visT     = (unsigned short*)(base + 0);
    unsigned short* vis_seg  = (unsigned short*)(base + 33554432);
    unsigned short* att2_pre = (unsigned short*)(base + 67108864);
    float*          se       = (float*)(base + 100663296);
    float*          P        = (float*)(base + 113246208);
    unsigned short* pse      = (unsigned short*)(base + 125829120);
    unsigned short* gbuf     = (unsigned short*)(base + 127926272);
    float*          att1buf  = (float*)(base + 130023424);
    unsigned short* avg      = (unsigned short*)(base + 132120576);
    unsigned short* vis_new  = (unsigned short*)(base + 134348800);
    char*           wbase    = base + 136445952;
    unsigned short* wT_visconv = (unsigned short*)(wbase + 0);
    unsigned short* wT_att2    = (unsigned short*)(wbase + 524288);
    unsigned short* wT_guide   = (unsigned short*)(wbase + 786432);
    unsigned short* wT_att1    = (unsigned short*)(wbase + 1835008);
    unsigned short* wT_out     = (unsigned short*)(wbase + 2097152);
    unsigned short* glob_bf    = (unsigned short*)(wbase + 2621440);
    unsigned short* WcombT     = (unsigned short*)(wbase + 4194304);
    float*          bcomb      = (float*)(wbase + 5767168);
    float*          text_part  = (float*)(wbase + 6291456);   // 2 MB
    float*          text_att   = (float*)(wbase + 8388608);   // 128 KB

    // merged prep: visual transpose + weight transposes + glob cast +
    // bcomb + text split-K partials
    prep_kernel<<<dim3(2595), 256, 0, stream>>>(
        visual, vis_conv_w, att2_w, guide_w, att1_w, out_conv_w, glob_w,
        text_feature, text_w, text_b, glob_b, guide_b,
        visT, wT_visconv, wT_att2, wT_guide, wT_att1, wT_out,
        glob_bf, text_part, bcomb);

    // Wcomb MFMA + vis_conv(+avg) + text_att reduction in ONE launch
    wcomb_visconv_kernel<<<dim3(192 + 1024 + 64), 256, 0, stream>>>(
        wT_guide, glob_bf, WcombT,
        visT, wT_visconv, vis_conv_b, vis_seg, avg,
        text_part, text_b, text_att);

    // att2_pre + P (both depend only on the previous launch) in ONE launch
    att2_p_kernel<<<dim3(512 + 768), 256, 0, stream>>>(
        vis_seg, wT_att2, att2_b, att2_pre,
        avg, WcombT, bcomb, P, gbuf);

    for (int m = 0; m < SQN_; m++) {
        if (m > 0) {
            mfma_gemm<64, 64, true, true, 0, true, 3><<<dim3(256), 256, 0, stream>>>(
                pse, 0, H_,
                wT_guide + 512, 0, 1024,
                nullptr, 0, P + (long long)(m - 1) * BS_ * H_, H_,
                gbuf, 0, H_, nullptr, nullptr, BS_, H_, H_);
        }
        mfma_gemm<64, 64, false, false, 0, false, 3><<<dim3(128), 256, 0, stream>>>(
            gbuf, 0, H_,
            wT_att1, 0, H_,
            att1_b, 0, nullptr, 0,
            att1buf, 0, A_, nullptr, nullptr, BS_, A_, H_);
        if (m < SQN_ - 1) {
            fused_att_kernel<false><<<dim3(BS_), 256, 0, stream>>>(
                att1buf, att2_pre, att3_w, att3_b, vis_seg,
                se + (long long)m * BS_ * H_, pse, att_out, m,
                nullptr, nullptr, nullptr);
        } else {
            fused_att_kernel<true><<<dim3(BS_), 256, 0, stream>>>(
                att1buf, att2_pre, att3_w, att3_b, vis_seg,
                nullptr, nullptr, att_out, m,
                se, text_att, vis_new);
        }
    }

    // vis_out = relu(vis_new @ out_conv_w + b), transposed store [b][h][s]
    mfma_gemm<64, 64, true, false, 1, false, 3><<<dim3(256), 256, 0, stream>>>(
        vis_new, 0, H_,
        wT_out, 0, H_,
        out_conv_b, 0, nullptr, 0,
        out, 0, 0, nullptr, nullptr, BS_, H_, H_);
}

// Round 10
// 159.093 us; speedup vs baseline: 1.1398x; 1.0213x over previous
//
#include <hip/hip_runtime.h>

#define B_   64
#define CIN_ 512
#define H_   512
#define V_   512
#define S_   32
#define T_   16
#define A_   256
#define SQN_ 3
#define BS_  2048   // B_*S_

typedef float  f32x4  __attribute__((ext_vector_type(4)));
typedef float  f32x2  __attribute__((ext_vector_type(2)));
typedef short  short8 __attribute__((ext_vector_type(8)));
typedef short  short4v __attribute__((ext_vector_type(4)));
typedef unsigned int uint4v __attribute__((ext_vector_type(4)));

__device__ __forceinline__ unsigned short f2bf(float f) {
    union { float f; unsigned int u; } v; v.f = f;
    unsigned int u = v.u;
    unsigned int r = (u + 0x7fffu + ((u >> 16) & 1u)) >> 16;
    return (unsigned short)r;
}
__device__ __forceinline__ float bf2f(unsigned short h) {
    union { unsigned int u; float f; } v; v.u = ((unsigned int)h) << 16;
    return v.f;
}

// fast tanh: (e-1)*rcp(e+1), e=exp(2x) via v_exp_f32; clamp keeps e finite.
__device__ __forceinline__ float fast_tanhf(float x) {
    float cx = fminf(fmaxf(x, -15.0f), 15.0f);
    float e  = __expf(2.0f * cx);
    return (e - 1.0f) * __builtin_amdgcn_rcpf(e + 1.0f);
}

// async global->LDS, 16 B per lane; lds dest = wave-uniform base + lane*16
__device__ __forceinline__ void gload16(const void* g, void* l) {
    __builtin_amdgcn_global_load_lds(
        (const __attribute__((address_space(1))) unsigned int*)g,
        (__attribute__((address_space(3))) unsigned int*)l,
        16, 0, 0);
}

template <int N> __device__ __forceinline__ void waitv() {
    asm volatile("s_waitcnt vmcnt(%0)" :: "n"(N) : "memory");
}

// ---------------------------------------------------------------------------
// prep_kernel (merged, one launch):
//   [0,128)      text split-K f32 partials: nt=id&7 (64n), kc=id>>3 (32k)
//   [128,131)    bcomb: 3 blocks (one per m), coalesced row-walk
//   [131,227)    glob_w f32 -> bf16 cast (8192 floats/block)
//   [227,547)    weight transposes (64x64)
//   [547,2595)   visual transpose-cast, DMA-staged [64k][128v] tiles
// ---------------------------------------------------------------------------
__global__ __launch_bounds__(256) void prep_kernel(
    const float* __restrict__ visual, const float* __restrict__ vis_conv_w,
    const float* __restrict__ att2_w, const float* __restrict__ guide_w,
    const float* __restrict__ att1_w, const float* __restrict__ out_conv_w,
    const float* __restrict__ glob_w, const float* __restrict__ text_feature,
    const float* __restrict__ text_w, const float* __restrict__ text_b,
    const float* __restrict__ glob_b, const float* __restrict__ guide_b,
    unsigned short* __restrict__ visT, unsigned short* __restrict__ wT_visconv,
    unsigned short* __restrict__ wT_att2, unsigned short* __restrict__ wT_guide,
    unsigned short* __restrict__ wT_att1, unsigned short* __restrict__ wT_out,
    unsigned short* __restrict__ glob_bf, float* __restrict__ text_part,
    float* __restrict__ bcomb)
{
    __shared__ __align__(16) char smem[32768];
    const int id  = blockIdx.x;
    const int tid = threadIdx.x;

    if (id < 128) {  // text split-K partial: [64m x 64n] over K=32, f32 exact
        const int nt = id & 7, kc = id >> 3;
        const int n0 = nt * 64, kbase = kc * 32;
        float* Ts = (float*)smem;                 // [64][33]
        float* Ws = (float*)smem + 64 * 33;       // [32][65]
        {
            const int m = tid >> 2, kk = (tid & 3) * 8;
            #pragma unroll
            for (int c = 0; c < 8; c += 4)
                *(f32x4*)&Ts[m * 33 + kk + c] =
                    *(const f32x4*)&text_feature[m * 512 + kbase + kk + c];
            const int kr = tid >> 3, nn = (tid & 7) * 8;
            #pragma unroll
            for (int c = 0; c < 8; c += 4)
                *(f32x4*)&Ws[kr * 65 + nn + c] =
                    *(const f32x4*)&text_w[(long long)(kbase + kr) * 512 + n0 + nn + c];
        }
        __syncthreads();
        const int tm = (tid >> 4) * 4, tn = (tid & 15) * 4;
        float acc[4][4] = {};
        for (int k = 0; k < 32; k++) {
            float a[4], b2[4];
            #pragma unroll
            for (int i = 0; i < 4; i++) a[i] = Ts[(tm + i) * 33 + k];
            #pragma unroll
            for (int j = 0; j < 4; j++) b2[j] = Ws[k * 65 + tn + j];
            #pragma unroll
            for (int i = 0; i < 4; i++)
                #pragma unroll
                for (int j = 0; j < 4; j++) acc[i][j] += a[i] * b2[j];
        }
        #pragma unroll
        for (int i = 0; i < 4; i++)
            #pragma unroll
            for (int j = 0; j < 4; j++)
                text_part[kc * (64 * 512) + (tm + i) * 512 + n0 + tn + j] =
                    acc[i][j] + (kc == 0 ? text_b[n0 + tn + j] : 0.0f);
        return;
    }
    if (id < 131) {  // bcomb[m][j] = glob_b[m] @ guide_w_top[:,j] + guide_b[j]
        const int m = id - 128;
        const int j2 = tid * 2;
        float a0 = guide_b[j2], a1 = guide_b[j2 + 1];
        const float* gb = glob_b + m * 512;
        #pragma unroll 8
        for (int k = 0; k < 512; k++) {
            const float g = gb[k];
            f32x2 w = *(const f32x2*)&guide_w[(long long)k * 512 + j2];  // coalesced
            a0 += g * w[0];
            a1 += g * w[1];
        }
        f32x2 o = {a0, a1};
        *(f32x2*)&bcomb[m * 512 + j2] = o;
        return;
    }
    if (id < 227) {  // glob cast: 8192 floats/block
        const int base = (id - 131) * 8192 + tid * 4;
        #pragma unroll
        for (int it = 0; it < 8; it++) {
            f32x4 v = *(const f32x4*)&glob_w[base + it * 1024];
            short4v o;
            #pragma unroll
            for (int c = 0; c < 4; c++) o[c] = (short)f2bf(v[c]);
            *(short4v*)&glob_bf[base + it * 1024] = o;
        }
        return;
    }

    if (id >= 547) {
        // visual transpose-cast: DMA-staged [64k][128v] tile
        const int q = id - 547;
        const int b = q >> 5, tile = q & 31;
        const int k0 = (tile >> 2) << 6;   // 0..448
        const int v0 = (tile & 3) << 7;    // 0,128,256,384
        const float* src = visual + (long long)b * 262144;
        unsigned short* dst = visT + (long long)b * 262144;
        float* tl = (float*)smem;          // [64][128] linear, 32 KB

        const int wave = tid >> 6, lane = tid & 63;
        #pragma unroll
        for (int i = 0; i < 8; i++) {
            const int r2 = wave * 16 + i * 2;
            gload16(&src[(long long)(k0 + r2 + (lane >> 5)) * 512 + v0 + (lane & 31) * 4],
                    &tl[r2 * 128]);
        }
        __syncthreads();

        const int kl = (tid & 7) * 8;      // 0..56
        const int vb = tid >> 3;           // 0..31
        #pragma unroll
        for (int jv = 0; jv < 4; jv++) {
            const int v = vb + jv * 32;
            short8 o;
            #pragma unroll
            for (int i = 0; i < 8; i++)
                o[i] = (short)f2bf(tl[(kl + i) * 128 + v]);
            *(short8*)&dst[(long long)(v0 + v) * 512 + k0 + kl] = o;
        }
        return;
    }

    // 64x64 transpose-cast (weights): src f32 [Kd][Nd] -> dst bf16 [Nd][Kd]
    const float* src; unsigned short* dst; int Kd, Nd, tile;
    if (id < 291)      { tile = id - 227; src = vis_conv_w; dst = wT_visconv; Kd = 512;  Nd = 512; }
    else if (id < 323) { tile = id - 291; src = att2_w;     dst = wT_att2;    Kd = 512;  Nd = 256; }
    else if (id < 451) { tile = id - 323; src = guide_w;    dst = wT_guide;   Kd = 1024; Nd = 512; }
    else if (id < 483) { tile = id - 451; src = att1_w;     dst = wT_att1;    Kd = 512;  Nd = 256; }
    else               { tile = id - 483; src = out_conv_w; dst = wT_out;     Kd = 512;  Nd = 512; }

    unsigned int* tl = (unsigned int*)smem;  // [64][65]
    const int xw = Nd >> 6;
    const int n0 = (tile % xw) << 6, k0 = (tile / xw) << 6;
    {
        const int r = tid >> 4;
        const int c4 = (tid & 15) * 4;
        #pragma unroll
        for (int j = 0; j < 4; j++) {
            const int row = j * 16 + r;
            f32x4 v = *(const f32x4*)&src[(long long)(k0 + row) * Nd + n0 + c4];
            #pragma unroll
            for (int c2 = 0; c2 < 4; c2++)
                tl[row * 65 + c4 + c2] = f2bf(v[c2]);
        }
    }
    __syncthreads();
    {
        const int v = tid >> 2, cq = (tid & 3) * 16;
        short8 o0, o1;
        #pragma unroll
        for (int j = 0; j < 8; j++) o0[j] = (short)tl[(cq + j) * 65 + v];
        #pragma unroll
        for (int j = 0; j < 8; j++) o1[j] = (short)tl[(cq + 8 + j) * 65 + v];
        *(short8*)&dst[(long long)(n0 + v) * Kd + k0 + cq] = o0;
        *(short8*)&dst[(long long)(n0 + v) * Kd + k0 + cq + 8] = o1;
    }
}

// ---------------------------------------------------------------------------
// GEMM body (r4-proven): DEPTH-deep counted-vmcnt staging (never vmcnt(0) in
// the main loop), two barriers per K-step, both-sides LDS XOR swizzle.
// DEPTH=2 for merged big kernels (4 blocks/CU), DEPTH=3 for small grids.
// ---------------------------------------------------------------------------
template <int BM, int BN, bool RELU, bool OUT_BF16, int OUT_MODE, bool ACC_INIT, int DEPTH>
__device__ __forceinline__ void gemm_body(
    char* pool, int bid, int nwg,
    const unsigned short* __restrict__ A, long long aBatch, int lda,
    const unsigned short* __restrict__ Bt, long long bBatch, int ldb,
    const float* __restrict__ bias, long long biasBatch,
    const float* __restrict__ Cinit, int ldci,
    void* __restrict__ C, long long cBatch, int ldc,
    void* __restrict__ C2, unsigned short* __restrict__ avg_out,
    int M, int N, int K)
{
    constexpr int WM = BM / 2, WN = BN / 2;
    constexpr int FI = WM / 16, FJ = WN / 16;
    constexpr int LOADS = BM / 64 + BN / 64;   // gloads per wave per stage (2 or 4)
    constexpr bool CT_EN  = (OUT_MODE != 1);
    constexpr bool CT_F32 = CT_EN && ((OUT_MODE == 0 && !OUT_BF16) || OUT_MODE == 3);
    constexpr int  CTS    = CT_F32 ? (BN + 4) : (BN + 8);
    constexpr int  KLOOP_B = DEPTH * (BM * 32 + BN * 32) * 2;
    constexpr int  CT_B    = CT_EN ? (BM * CTS * (CT_F32 ? 4 : 2)) : 0;
    constexpr int  MAIN_B  = (KLOOP_B > CT_B ? KLOOP_B : CT_B);
    unsigned short* As = (unsigned short*)pool;
    unsigned short* Bs = As + DEPTH * BM * 32;
    float* avgl = (float*)(pool + MAIN_B);

    // XCD-chunked bijective swizzle (m204)
    const int q8 = nwg >> 3, r8 = nwg & 7;
    const int xcd = bid & 7, lid = bid >> 3;
    const int logical = (xcd < r8 ? xcd * (q8 + 1)
                                  : r8 * (q8 + 1) + (xcd - r8) * q8) + lid;

    const int ntiles = N / BN;
    const int tilesPerBatch = (M / BM) * ntiles;
    const int batch = logical / tilesPerBatch;
    const int t     = logical % tilesPerBatch;
    const int tm0 = (t / ntiles) * BM;
    const int tn0 = (t % ntiles) * BN;
    const unsigned short* Ab = A + (long long)batch * aBatch;
    const unsigned short* Bb = Bt + (long long)batch * bBatch;

    const int tid  = threadIdx.x;
    const int lane = tid & 63;
    const int wave = tid >> 6;
    const int wm = (wave >> 1) * WM;
    const int wn = (wave & 1) * WN;
    const int lr = lane & 15;
    const int lk = (lane >> 4) * 8;
    const int rsub = lane >> 2;
    // pre-swizzled global 16B slot: (lane&3) ^ ((lane>>3)&3) == (lane&3) ^ ((row>>1)&3)
    const int g8s = ((lane & 3) ^ ((lane >> 3) & 3)) * 8;
    // frag-read elem offset with matching XOR (row key = (lr>>1)&3)
    const int lks = lk ^ (((lr >> 1) & 3) << 3);

    auto stage = [&](int buf, int k0) {
        #pragma unroll
        for (int i = 0; i < BM / 64; i++) {
            const int rbase = wave * (BM / 4) + i * 16;
            gload16(&Ab[(long long)(tm0 + rbase + rsub) * lda + k0 + g8s],
                    &As[buf * (BM * 32) + rbase * 32]);
        }
        #pragma unroll
        for (int i = 0; i < BN / 64; i++) {
            const int rbase = wave * (BN / 4) + i * 16;
            gload16(&Bb[(long long)(tn0 + rbase + rsub) * ldb + k0 + g8s],
                    &Bs[buf * (BN * 32) + rbase * 32]);
        }
    };

    f32x4 acc[FI][FJ] = {};
    const int nk = K >> 5;

    #pragma unroll
    for (int d = 0; d < DEPTH - 1; d++)
        if (d < nk) stage(d, d << 5);

    int cur = 0;
    for (int kt = 0; kt < nk; kt++) {
        if (kt + DEPTH - 1 < nk) {
            const int nb = cur + DEPTH - 1;
            stage(nb >= DEPTH ? nb - DEPTH : nb, (kt + DEPTH - 1) << 5);
        }
        // counted wait: own step-kt loads landed; deeper prefetches stay in
        // flight across the barrier (never vmcnt(0) in the main loop)
        if constexpr (DEPTH == 2) {
            if (kt + 1 < nk) waitv<LOADS>(); else waitv<0>();
        } else {
            if (kt + 2 < nk)      waitv<2 * LOADS>();
            else if (kt + 1 < nk) waitv<LOADS>();
            else                  waitv<0>();
        }
        __builtin_amdgcn_s_barrier();   // publish: every wave's kt-loads landed

        const unsigned short* Ac = As + cur * (BM * 32);
        const unsigned short* Bc = Bs + cur * (BN * 32);
        short8 a[FI], b[FJ];
        #pragma unroll
        for (int i = 0; i < FI; i++)
            a[i] = *(const short8*)&Ac[(wm + i * 16 + lr) * 32 + lks];
        #pragma unroll
        for (int j = 0; j < FJ; j++)
            b[j] = *(const short8*)&Bc[(wn + j * 16 + lr) * 32 + lks];
        #pragma unroll
        for (int i = 0; i < FI; i++)
            #pragma unroll
            for (int j = 0; j < FJ; j++)
                acc[i][j] = __builtin_amdgcn_mfma_f32_16x16x32_bf16(
                    a[i], b[j], acc[i][j], 0, 0, 0);
        __builtin_amdgcn_sched_barrier(0);  // pin reads+MFMA above the barrier
        __builtin_amdgcn_s_barrier();       // all reads of buf 'cur' retired
        cur = (cur + 1 == DEPTH) ? 0 : cur + 1;
    }

    const int erow = (lane >> 4) * 4;
    const int ecol = lane & 15;

    if constexpr (OUT_MODE == 1) {
        #pragma unroll
        for (int i = 0; i < FI; i++) {
            #pragma unroll
            for (int j = 0; j < FJ; j++) {
                const int gcol = tn0 + wn + j * 16 + ecol;
                const float bv = bias ? bias[gcol] : 0.0f;
                const int grow0 = tm0 + wm + i * 16 + erow;
                const int bb = grow0 >> 5, ss = grow0 & 31;
                f32x4 o;
                #pragma unroll
                for (int r = 0; r < 4; r++) o[r] = fmaxf(acc[i][j][r] + bv, 0.0f);
                *(f32x4*)&((float*)C)[(long long)bb * (H_ * S_) + gcol * S_ + ss] = o;
            }
        }
        return;
    } else {
        __syncthreads();
        unsigned short* CTh = (unsigned short*)pool;
        float*          CTf = (float*)pool;

        #pragma unroll
        for (int i = 0; i < FI; i++) {
            #pragma unroll
            for (int j = 0; j < FJ; j++) {
                const int lcol = wn + j * 16 + ecol;
                const int gcol = tn0 + lcol;
                const float bv = bias ? bias[(long long)batch * biasBatch + gcol] : 0.0f;
                float csum = 0.0f;
                #pragma unroll
                for (int r = 0; r < 4; r++) {
                    const int lrow = wm + i * 16 + erow + r;
                    float v = acc[i][j][r] + bv;
                    if (ACC_INIT) v += Cinit[(long long)(tm0 + lrow) * ldci + gcol];
                    if (RELU) v = fmaxf(v, 0.0f);
                    if constexpr (CT_F32) CTf[lrow * CTS + lcol] = v;
                    else                  CTh[lrow * CTS + lcol] = f2bf(v);
                    if constexpr (OUT_MODE == 2) csum += v;
                }
                if constexpr (OUT_MODE == 2) {
                    csum += __shfl_xor(csum, 16, 64);
                    csum += __shfl_xor(csum, 32, 64);
                    if (lane < 16)
                        avgl[((wm >> 4) + i) * BN + wn + j * 16 + lane] = csum;
                }
            }
        }
        __syncthreads();

        if constexpr (CT_F32) {
            constexpr int ITERS = (BM * BN) / 1024;
            #pragma unroll
            for (int it = 0; it < ITERS; it++) {
                const int flat = it * 1024 + tid * 4;
                const int row = flat / BN, col = flat % BN;
                f32x4 vv = *(const f32x4*)&CTf[row * CTS + col];
                if constexpr (OUT_MODE == 3) {
                    if (batch == 0) {
                        short4v p;
                        #pragma unroll
                        for (int c = 0; c < 4; c++) p[c] = (short)f2bf(fmaxf(vv[c], 0.0f));
                        *(short4v*)&((unsigned short*)C2)[(long long)(tm0 + row) * ldc + tn0 + col] = p;
                    } else {
                        *(f32x4*)&((float*)C)[(long long)(batch - 1) * cBatch +
                                              (long long)(tm0 + row) * ldc + tn0 + col] = vv;
                    }
                } else {
                    *(f32x4*)&((float*)C)[(long long)batch * cBatch +
                                          (long long)(tm0 + row) * ldc + tn0 + col] = vv;
                }
            }
        } else {
            constexpr int ITERS = (BM * BN) / 2048;
            #pragma unroll
            for (int it = 0; it < ITERS; it++) {
                const int flat = it * 2048 + tid * 8;
                const int row = flat / BN, col = flat % BN;
                short8 vv = *(const short8*)&CTh[row * CTS + col];
                *(short8*)&((unsigned short*)C)[(long long)batch * cBatch +
                                                (long long)(tm0 + row) * ldc + tn0 + col] = vv;
            }
        }

        if constexpr (OUT_MODE == 2) {
            const int s = tid >> 5, hq = (tid & 31) * 4;
            short4v pk;
            #pragma unroll
            for (int c = 0; c < 4; c++)
                pk[c] = (short)f2bf(avgl[s * BN + hq + c] * (1.0f / 16.0f));
            *(short4v*)&avg_out[((long long)batch * 32 + (tm0 >> 4) + s) * H_ + tn0 + hq] = pk;
        }
    }
}

// Standalone wrapper (guide / att1 / out_conv) — small grids, DEPTH=3
template <int BM, int BN, bool RELU, bool OUT_BF16, int OUT_MODE, bool ACC_INIT, int DEPTH>
__global__ __launch_bounds__(256) void mfma_gemm(
    const unsigned short* A, long long aBatch, int lda,
    const unsigned short* Bt, long long bBatch, int ldb,
    const float* bias, long long biasBatch,
    const float* Cinit, int ldci,
    void* C, long long cBatch, int ldc,
    void* C2, unsigned short* avg_out,
    int M, int N, int K)
{
    constexpr bool CT_EN  = (OUT_MODE != 1);
    constexpr bool CT_F32 = CT_EN && ((OUT_MODE == 0 && !OUT_BF16) || OUT_MODE == 3);
    constexpr int  CTS    = CT_F32 ? (BN + 4) : (BN + 8);
    constexpr int  KLOOP_B = DEPTH * (BM * 32 + BN * 32) * 2;
    constexpr int  CT_B    = CT_EN ? (BM * CTS * (CT_F32 ? 4 : 2)) : 0;
    constexpr int  MAIN_B  = (KLOOP_B > CT_B ? KLOOP_B : CT_B);
    constexpr int  AVG_B   = (OUT_MODE == 2) ? (BM / 16) * BN * 4 : 0;
    __shared__ __align__(16) char pool[MAIN_B + AVG_B];
    gemm_body<BM, BN, RELU, OUT_BF16, OUT_MODE, ACC_INIT, DEPTH>(
        pool, blockIdx.x, gridDim.x,
        A, aBatch, lda, Bt, bBatch, ldb, bias, biasBatch, Cinit, ldci,
        C, cBatch, ldc, C2, avg_out, M, N, K);
}

// Merged launch A: Wcomb (192) + vis_conv (1024) + text_att sum (64), DEPTH=2
// pool: 128x128 OUT_MODE2 -> max(2*16KB, CT 34816) + AVG 4096 = 38912 -> 4 blk/CU
__global__ __launch_bounds__(256) void wcomb_visconv_kernel(
    const unsigned short* wT_guide, const unsigned short* glob_bf,
    unsigned short* WcombT,
    const unsigned short* visT, const unsigned short* wT_visconv,
    const float* vis_conv_b, unsigned short* vis_seg, unsigned short* avg,
    const float* __restrict__ text_part, const float* __restrict__ text_b,
    float* __restrict__ text_att)
{
    __shared__ __align__(16) char pool[38912];
    if (blockIdx.x < 192) {
        gemm_body<64, 64, false, true, 0, false, 2>(pool, blockIdx.x, 192,
            wT_guide, 0, 1024,
            glob_bf, (long long)H_ * H_, H_,
            nullptr, 0, nullptr, 0,
            WcombT, (long long)H_ * H_, H_, nullptr, nullptr, H_, H_, H_);
    } else if (blockIdx.x < 1216) {
        gemm_body<128, 128, true, true, 2, false, 2>(pool, blockIdx.x - 192, 1024,
            visT, (long long)V_ * CIN_, CIN_,
            wT_visconv, 0, CIN_,
            vis_conv_b, 0, nullptr, 0,
            vis_seg, (long long)V_ * H_, H_, nullptr, avg, V_, H_, CIN_);
    } else {
        // text_att[b][h] = text_b[h] + sum_p text_part[p][b][h]  (64 blocks)
        const int b = blockIdx.x - 1216;
        const int tid = threadIdx.x;
        #pragma unroll
        for (int hh = 0; hh < 2; hh++) {
            const int h = tid + hh * 256;
            float s = text_b[h];
            #pragma unroll
            for (int p = 0; p < 16; p++)
                s += text_part[p * (64 * 512) + b * 512 + h];
            text_att[b * 512 + h] = s;
        }
    }
}

// Merged launch B: att2 (512 blocks) + P (768 blocks), DEPTH=2
// pool: max(2*16KB, CT 34816) = 34816 -> 4 blk/CU
__global__ __launch_bounds__(256) void att2_p_kernel(
    const unsigned short* vis_seg, const unsigned short* wT_att2,
    const float* att2_b, unsigned short* att2_pre,
    const unsigned short* avg, const unsigned short* WcombT,
    const float* bcomb, float* P, unsigned short* gbuf)
{
    __shared__ __align__(16) char pool[34816];
    if (blockIdx.x < 512) {
        gemm_body<128, 128, false, true, 0, false, 2>(pool, blockIdx.x, 512,
            vis_seg, (long long)V_ * H_, H_,
            wT_att2, 0, H_,
            att2_b, 0, nullptr, 0,
            att2_pre, (long long)V_ * A_, A_, nullptr, nullptr, V_, A_, H_);
    } else {
        gemm_body<64, 64, false, false, 3, false, 2>(pool, blockIdx.x - 512, 768,
            avg, 0, H_,
            WcombT, (long long)H_ * H_, H_,
            bcomb, H_, nullptr, 0,
            P, (long long)BS_ * H_, H_, gbuf, nullptr, BS_, H_, H_);
    }
}

// ---------------------------------------------------------------------------
// tanh-attention + softmax(16) + weighted pool; LAST folds fuse softmax.
// att1 arrives as TWO split-K f32 slabs (summed here, + att1_b).
// text_att is precomputed (launch A) — LAST blocks just load 512 floats.
// ---------------------------------------------------------------------------
template <bool LAST>
__global__ __launch_bounds__(256) void fused_att_kernel(
    const float* __restrict__ att1,          // [2][BS][A] f32 split-K slabs
    const float* __restrict__ att1b,         // [A] bias
    const unsigned short* __restrict__ att2_pre,
    const float* __restrict__ att3_w,
    const float* __restrict__ att3_b,
    const unsigned short* __restrict__ vis_seg,
    float* __restrict__ se_m,
    unsigned short* __restrict__ pse,
    float* __restrict__ att_out, int m,
    const float* __restrict__ se_base,
    const float* __restrict__ text_att,      // [64][512] f32 (LAST)
    unsigned short* __restrict__ vis_new)
{
    const int bs = blockIdx.x, tid = threadIdx.x;
    const int wave = tid >> 6, lane = tid & 63;
    __shared__ float logits[T_], wts[T_];
    __shared__ float part[3][512];
    __shared__ float redf[4][3];
    __shared__ float swf[3];
    __shared__ float tsh[512];

    if constexpr (LAST) {
        const int b = bs >> 5;
        #pragma unroll
        for (int hh = 0; hh < 2; hh++) {
            const int h = tid + hh * 256;
            tsh[h] = text_att[b * 512 + h];
        }
    }

    f32x4 a1r;
    {
        f32x4 p0 = *(const f32x4*)&att1[(long long)bs * A_ + lane * 4];
        f32x4 p1 = *(const f32x4*)&att1[(long long)BS_ * A_ + (long long)bs * A_ + lane * 4];
        f32x4 bb = *(const f32x4*)&att1b[lane * 4];
        a1r = p0 + p1 + bb;
    }
    f32x4 w3r = *(const f32x4*)&att3_w[lane * 4];

    #pragma unroll
    for (int qq = 0; qq < 4; qq++) {
        const int t = wave * 4 + qq;
        short4v ap = *(const short4v*)&att2_pre[(long long)(bs * T_ + t) * A_ + lane * 4];
        float x = 0.f;
        #pragma unroll
        for (int c = 0; c < 4; c++)
            x += fast_tanhf(a1r[c] + bf2f((unsigned short)ap[c])) * w3r[c];
        #pragma unroll
        for (int off = 32; off > 0; off >>= 1) x += __shfl_down(x, off, 64);
        if (lane == 0) logits[t] = x + att3_b[0];
    }
    __syncthreads();
    // wave-parallel 16-logit softmax (lanes 0-15 of wave 0)
    if (tid < 16) {
        float x = logits[tid];
        float mx = x;
        #pragma unroll
        for (int o = 8; o > 0; o >>= 1) mx = fmaxf(mx, __shfl_xor(mx, o, 64));
        float e = __expf(x - mx);
        float s = e;
        #pragma unroll
        for (int o = 8; o > 0; o >>= 1) s += __shfl_xor(s, o, 64);
        wts[tid] = e * __builtin_amdgcn_rcpf(s);
    }
    __syncthreads();
    if (tid < T_) att_out[bs * (T_ * SQN_) + tid * SQN_ + m] = wts[tid];

    const int slot = tid & 63, quarter = tid >> 6;
    float s[8] = {};
    #pragma unroll
    for (int tt = 0; tt < 4; tt++) {
        const int t = quarter * 4 + tt;
        short8 vv = *(const short8*)&vis_seg[(long long)(bs * T_ + t) * H_ + slot * 8];
        const float w = wts[t];
        #pragma unroll
        for (int c = 0; c < 8; c++) s[c] += bf2f((unsigned short)vv[c]) * w;
    }
    if (quarter) {
        #pragma unroll
        for (int c = 0; c < 8; c++) part[quarter - 1][slot * 8 + c] = s[c];
    }
    __syncthreads();
    if (quarter == 0) {
        #pragma unroll
        for (int c = 0; c < 8; c++)
            s[c] += part[0][slot * 8 + c] + part[1][slot * 8 + c] + part[2][slot * 8 + c];
    }

    if constexpr (!LAST) {
        if (quarter == 0) {
            f32x4 o0 = {s[0], s[1], s[2], s[3]};
            f32x4 o1 = {s[4], s[5], s[6], s[7]};
            *(f32x4*)&se_m[(long long)bs * H_ + slot * 8] = o0;
            *(f32x4*)&se_m[(long long)bs * H_ + slot * 8 + 4] = o1;
            short8 p;
            #pragma unroll
            for (int c = 0; c < 8; c++) p[c] = (short)f2bf(s[c]);
            *(short8*)&pse[(long long)bs * H_ + slot * 8] = p;
        }
    } else {
        const float* se0 = se_base + (long long)bs * H_;
        const float* se1 = se_base + (long long)BS_ * H_ + (long long)bs * H_;

        float p0 = 0.f, p1 = 0.f, p2 = 0.f;
        {
            const int h2 = tid * 2;
            float t0 = tsh[h2], t1 = tsh[h2 + 1];
            p0 = se0[h2] * t0 + se0[h2 + 1] * t1;
            p1 = se1[h2] * t0 + se1[h2 + 1] * t1;
        }
        if (quarter == 0) {
            #pragma unroll
            for (int c = 0; c < 8; c++) p2 += s[c] * tsh[slot * 8 + c];
        }
        #pragma unroll
        for (int off = 32; off > 0; off >>= 1) {
            p0 += __shfl_down(p0, off, 64);
            p1 += __shfl_down(p1, off, 64);
            p2 += __shfl_down(p2, off, 64);
        }
        if (lane == 0) { redf[wave][0] = p0; redf[wave][1] = p1; redf[wave][2] = p2; }
        __syncthreads();
        if (tid == 0) {
            float d0 = redf[0][0] + redf[1][0] + redf[2][0] + redf[3][0];
            float d1 = redf[0][1] + redf[1][1] + redf[2][1] + redf[3][1];
            float d2 = redf[0][2] + redf[1][2] + redf[2][2] + redf[3][2];
            float mx = fmaxf(d0, fmaxf(d1, d2));
            float e0 = __expf(d0 - mx), e1 = __expf(d1 - mx), e2 = __expf(d2 - mx);
            float inv = 1.0f / (e0 + e1 + e2);
            swf[0] = e0 * inv; swf[1] = e1 * inv; swf[2] = e2 * inv;
        }
        __syncthreads();
        if (quarter == 0) {
            const float w0 = swf[0], w1 = swf[1], w2 = swf[2];
            short8 p;
            #pragma unroll
            for (int c = 0; c < 8; c++) {
                const int h = slot * 8 + c;
                p[c] = (short)f2bf(w0 * se0[h] + w1 * se1[h] + w2 * s[c]);
            }
            *(short8*)&vis_new[(long long)bs * H_ + slot * 8] = p;
        }
    }
}

extern "C" void kernel_launch(void* const* d_in, const int* in_sizes, int n_in,
                              void* d_out, int out_size, void* d_ws, size_t ws_size,
                              hipStream_t stream)
{
    const float* visual       = (const float*)d_in[0];
    const float* text_feature = (const float*)d_in[1];
    const float* vis_conv_w   = (const float*)d_in[2];
    const float* vis_conv_b   = (const float*)d_in[3];
    const float* glob_w       = (const float*)d_in[4];
    const float* glob_b       = (const float*)d_in[5];
    const float* guide_w      = (const float*)d_in[6];
    const float* guide_b      = (const float*)d_in[7];
    const float* att1_w       = (const float*)d_in[8];
    const float* att1_b       = (const float*)d_in[9];
    const float* att2_w       = (const float*)d_in[10];
    const float* att2_b       = (const float*)d_in[11];
    const float* att3_w       = (const float*)d_in[12];
    const float* att3_b       = (const float*)d_in[13];
    const float* out_conv_w   = (const float*)d_in[14];
    const float* out_conv_b   = (const float*)d_in[15];
    const float* text_w       = (const float*)d_in[16];
    const float* text_b       = (const float*)d_in[17];
    float* out = (float*)d_out;
    float* att_out = out + (B_ * H_ * S_);

    char* base = (char*)d_ws;
    unsigned short* visT     = (unsigned short*)(base + 0);
    unsigned short* vis_seg  = (unsigned short*)(base + 33554432);
    unsigned short* att2_pre = (unsigned short*)(base + 67108864);
    float*          se       = (float*)(base + 100663296);
    float*          P        = (float*)(base + 113246208);
    unsigned short* pse      = (unsigned short*)(base + 125829120);
    unsigned short* gbuf     = (unsigned short*)(base + 127926272);
    float*          att1buf  = (float*)(base + 130023424);  // slab0 2MB; slab1
    // reuses the dead `avg` region (130023424+2MB..134217728 < vis_new)
    unsigned short* avg      = (unsigned short*)(base + 132120576);
    unsigned short* vis_new  = (unsigned short*)(base + 134348800);
    char*           wbase    = base + 136445952;
    unsigned short* wT_visconv = (unsigned short*)(wbase + 0);
    unsigned short* wT_att2    = (unsigned short*)(wbase + 524288);
    unsigned short* wT_guide   = (unsigned short*)(wbase + 786432);
    unsigned short* wT_att1    = (unsigned short*)(wbase + 1835008);
    unsigned short* wT_out     = (unsigned short*)(wbase + 2097152);
    unsigned short* glob_bf    = (unsigned short*)(wbase + 2621440);
    unsigned short* WcombT     = (unsigned short*)(wbase + 4194304);
    float*          bcomb      = (float*)(wbase + 5767168);
    float*          text_part  = (float*)(wbase + 6291456);   // 2 MB
    float*          text_att   = (float*)(wbase + 8388608);   // 128 KB

    // merged prep: visual transpose + weight transposes + glob cast +
    // bcomb + text split-K partials
    prep_kernel<<<dim3(2595), 256, 0, stream>>>(
        visual, vis_conv_w, att2_w, guide_w, att1_w, out_conv_w, glob_w,
        text_feature, text_w, text_b, glob_b, guide_b,
        visT, wT_visconv, wT_att2, wT_guide, wT_att1, wT_out,
        glob_bf, text_part, bcomb);

    // Wcomb MFMA + vis_conv(+avg) + text_att reduction in ONE launch
    wcomb_visconv_kernel<<<dim3(192 + 1024 + 64), 256, 0, stream>>>(
        wT_guide, glob_bf, WcombT,
        visT, wT_visconv, vis_conv_b, vis_seg, avg,
        text_part, text_b, text_att);

    // att2_pre + P (both depend only on the previous launch) in ONE launch
    att2_p_kernel<<<dim3(512 + 768), 256, 0, stream>>>(
        vis_seg, wT_att2, att2_b, att2_pre,
        avg, WcombT, bcomb, P, gbuf);

    for (int m = 0; m < SQN_; m++) {
        if (m > 0) {
            mfma_gemm<64, 64, true, true, 0, true, 3><<<dim3(256), 256, 0, stream>>>(
                pse, 0, H_,
                wT_guide + 512, 0, 1024,
                nullptr, 0, P + (long long)(m - 1) * BS_ * H_, H_,
                gbuf, 0, H_, nullptr, nullptr, BS_, H_, H_);
        }
        // att1 split-K=2: two K-halves as "batches" -> 256 blocks (1/CU),
        // f32 partial slabs summed (+att1_b) inside fused_att. Exact f32 add.
        mfma_gemm<64, 64, false, false, 0, false, 3><<<dim3(256), 256, 0, stream>>>(
            gbuf, 256, H_,
            wT_att1, 256, H_,
            nullptr, 0, nullptr, 0,
            att1buf, (long long)BS_ * A_, A_, nullptr, nullptr, BS_, A_, 256);
        if (m < SQN_ - 1) {
            fused_att_kernel<false><<<dim3(BS_), 256, 0, stream>>>(
                att1buf, att1_b, att2_pre, att3_w, att3_b, vis_seg,
                se + (long long)m * BS_ * H_, pse, att_out, m,
                nullptr, nullptr, nullptr);
        } else {
            fused_att_kernel<true><<<dim3(BS_), 256, 0, stream>>>(
                att1buf, att1_b, att2_pre, att3_w, att3_b, vis_seg,
                nullptr, nullptr, att_out, m,
                se, text_att, vis_new);
        }
    }

    // vis_out = relu(vis_new @ out_conv_w + b), transposed store [b][h][s]
    mfma_gemm<64, 64, true, false, 1, false, 3><<<dim3(256), 256, 0, stream>>>(
        vis_new, 0, H_,
        wT_out, 0, H_,
        out_conv_b, 0, nullptr, 0,
        out, 0, 0, nullptr, nullptr, BS_, H_, H_);
}